// Round 15
// baseline (509.218 us; speedup 1.0000x reference)
//
#include <hip/hip_runtime.h>
#include <hip/hip_bf16.h>
#include <math.h>
#include <stdint.h>

#define NTOK 1024
#define CT   768
#define CS   384
#define CP   16
#define NH   16
#define DH   48
#define NBLK 4
#define NL   8
#define NKEY 32
#define KTOT 40
#define SCALE_ 0.14433756729740643f   // 1/sqrt(48)

typedef __attribute__((ext_vector_type(8))) short short8;
typedef __attribute__((ext_vector_type(4))) float f32x4;
typedef __attribute__((ext_vector_type(2))) unsigned int u32x2;

#define AS1 __attribute__((address_space(1)))
#define AS3 __attribute__((address_space(3)))

__device__ __forceinline__ float sigmoidf_(float x) {
    return 1.0f / (1.0f + __expf(-x));
}
__device__ __forceinline__ float bf2f(unsigned short u) {
    union { unsigned int i; float f; } v; v.i = (unsigned int)u << 16; return v.f;
}
__device__ __forceinline__ unsigned short f2bf(float f) {
    return __bfloat16_as_ushort(__float2bfloat16(f));
}

__device__ __forceinline__ void gl_lds16(const void* g, void* l) {
    __builtin_amdgcn_global_load_lds((const AS1 void*)(uintptr_t)g,
                                     (AS3 void*)(uintptr_t)l, 16, 0, 0);
}

// ---------------------------------------------------------------------------
// Small prep kernel (384 thr): topk (b<256), sprep (256..1280), biasprep.
// ---------------------------------------------------------------------------
struct PrepArgs {
    const float* X_L; int* idx;
    const float* S; const float* g1; const float* g2;
    __hip_bfloat16* S_bf; __hip_bfloat16* snb;
    const float* bq; const float* sg_b; const float* tsg_b;
    float* qb; float* sb2;
};

__global__ __launch_bounds__(384)
void prep_kernel(PrepArgs pa) {
    __shared__ float ls[12];
    const int t = threadIdx.x;
    const int b = blockIdx.x;

    if (b < 256) {
        const int w = t >> 6;
        if (w >= 4) return;
        const int l = t & 63;
        const int n = b * 4 + w;
        const float* X = pa.X_L;
        int* idx = pa.idx;

        const float x0 = X[n * 3 + 0], x1 = X[n * 3 + 1], x2 = X[n * 3 + 2];
        float d[16];
        unsigned long long lkey = ~0ull;
#pragma unroll
        for (int j = 0; j < 16; ++j) {
            int m = j * 64 + l;
            float dx = x0 - X[m * 3 + 0];
            float dy = x1 - X[m * 3 + 1];
            float dz = x2 - X[m * 3 + 2];
            float v = dx * dx + dy * dy + dz * dz;
            d[j] = v;
            unsigned long long key =
                ((unsigned long long)__float_as_uint(v) << 32) | (unsigned int)m;
            lkey = key < lkey ? key : lkey;
        }
        if (l < NL) {
            int loc = n + l - NL / 2;
            loc = loc < 0 ? 0 : (loc > NTOK - 1 ? NTOK - 1 : loc);
            idx[n * KTOT + l] = loc;
        }
        for (int it = 0; it < NKEY; ++it) {
            unsigned long long rk = lkey;
#pragma unroll
            for (int s = 32; s > 0; s >>= 1) {
                unsigned long long o = __shfl_xor(rk, s, 64);
                rk = o < rk ? o : rk;
            }
            unsigned int win = (unsigned int)rk;
            if (l == 0) idx[n * KTOT + NL + it] = (int)win;
            if ((int)(win & 63) == l) {
                int jw = (int)(win >> 6);
                unsigned long long nk = ~0ull;
#pragma unroll
                for (int j = 0; j < 16; ++j) {
                    if (j == jw) d[j] = INFINITY;
                    unsigned long long key =
                        ((unsigned long long)__float_as_uint(d[j]) << 32) |
                        (unsigned int)(j * 64 + l);
                    nk = key < nk ? key : nk;
                }
                lkey = nk;
            }
        }
        return;
    }

    if (b < 1280) {
        int r = b - 256;
        int wid = t >> 6, l = t & 63;
        float v = pa.S[r * CS + t];
        float s = v;
#pragma unroll
        for (int m = 32; m > 0; m >>= 1) s += __shfl_xor(s, m, 64);
        if (l == 0) ls[wid] = s;
        __syncthreads();
        float mean = (ls[0] + ls[1] + ls[2] + ls[3] + ls[4] + ls[5]) * (1.0f / CS);
        float d = v - mean;
        float q = d * d;
#pragma unroll
        for (int m = 32; m > 0; m >>= 1) q += __shfl_xor(q, m, 64);
        if (l == 0) ls[6 + wid] = q;
        __syncthreads();
        float rstd = rsqrtf((ls[6] + ls[7] + ls[8] + ls[9] + ls[10] + ls[11]) *
                            (1.0f / CS) + 1e-5f);
        float ln = d * rstd;
        pa.S_bf[r * CS + t] = __float2bfloat16(v);
#pragma unroll
        for (int j = 0; j < 8; ++j) {
            const float* g = ((j & 1) ? pa.g2 : pa.g1) + (j >> 1) * CS;
            pa.snb[((size_t)j * NTOK + r) * CS + t] = __float2bfloat16(ln * g[t]);
        }
        return;
    }

    {
        int tt = (b - 1280) * 384 + t;
        if (tt < NBLK * 3072) {
            int i = tt / 3072, c = tt % 3072;
            pa.qb[tt] = (c < 768) ? pa.bq[i * 768 + c] : 0.0f;
        }
        if (tt < NBLK * 1536) {
            int i = tt / 1536, c = tt % 1536;
            pa.sb2[tt] = (c < 768) ? pa.sg_b[i * 768 + c] : pa.tsg_b[i * 768 + c - 768];
        }
    }
}

// ---------------------------------------------------------------------------
// AdaLN apply: an = bf16( sigmoid(SIG) * LN(A) + SH ). One block per row.
// ---------------------------------------------------------------------------
__global__ __launch_bounds__(256)
void adaapply_kernel(const float* __restrict__ A,
                     const __hip_bfloat16* __restrict__ SIG,
                     const __hip_bfloat16* __restrict__ SH,
                     __hip_bfloat16* __restrict__ an) {
    int r = blockIdx.x, t = threadIdx.x;
    int wid = t >> 6, l = t & 63;
    __shared__ float ls[8];
    const float* ar = A + (size_t)r * CT;
    float v0 = ar[t], v1 = ar[t + 256], v2 = ar[t + 512];
    float s = v0 + v1 + v2;
#pragma unroll
    for (int m = 32; m > 0; m >>= 1) s += __shfl_xor(s, m, 64);
    if (l == 0) ls[wid] = s;
    __syncthreads();
    float mean = (ls[0] + ls[1] + ls[2] + ls[3]) * (1.0f / CT);
    float d0 = v0 - mean, d1 = v1 - mean, d2 = v2 - mean;
    float q = d0 * d0 + d1 * d1 + d2 * d2;
#pragma unroll
    for (int m = 32; m > 0; m >>= 1) q += __shfl_xor(q, m, 64);
    if (l == 0) ls[4 + wid] = q;
    __syncthreads();
    float rstd = rsqrtf((ls[4] + ls[5] + ls[6] + ls[7]) * (1.0f / CT) + 1e-5f);
    size_t base = (size_t)r * CT;
    float dd[3] = {d0, d1, d2};
#pragma unroll
    for (int k = 0; k < 3; ++k) {
        int c = t + k * 256;
        float sg = sigmoidf_(__bfloat162float(SIG[base + c]));
        float sh = __bfloat162float(SH[base + c]);
        an[base + c] = __float2bfloat16(sg * dd[k] * rstd + sh);
    }
}

// ---------------------------------------------------------------------------
// Wide GEMM body: tile 128(M) x 64(N), BK=64, 4 waves (each 32x64).
// A: bf16 [M][K] via gl_lds16 (pre-swizzled source).
// B: fp32 W [K][Wld], staged reg->bf16->LDS transposed (fused convert).
// out = bf16(acc + cb[ocol]).
// ---------------------------------------------------------------------------
__device__ __forceinline__ void wide_body(
    const __hip_bfloat16* A, int K,
    const float* W, int Wld,
    const float* cb, __hip_bfloat16* out, int ldo,
    int row0, int wcol0, int ocol0,
    char* As0, char* As1, char* Bs0, char* Bs1) {
    const int tid = threadIdx.x;
    const int lane = tid & 63;
    const int wid = tid >> 6;
    char* Asb[2] = {As0, As1};
    char* Bsb[2] = {Bs0, Bs1};

    // A staging
    const int srow = tid >> 3;
    const int sg_e = (((tid & 7) ^ (srow & 7)) << 3);
    const __hip_bfloat16* ag = A + (size_t)(row0 + srow) * K + sg_e;
    const size_t r32K = (size_t)32 * K;

    // B staging: thread (kq, nq); k = kq*4+r, n = nq*4+j
    const int kq = tid >> 4;
    const int nq = tid & 15;
    const float* wp = W + (size_t)kq * 4 * Wld + wcol0 + nq * 4;
    f32x4 breg[4];

    const int l15 = lane & 15;
    const int lhi = lane >> 4;
    const int nIter = K >> 6;

    f32x4 acc[2][4];
#pragma unroll
    for (int i = 0; i < 2; ++i)
#pragma unroll
        for (int j = 0; j < 4; ++j) acc[i][j] = (f32x4){0.f, 0.f, 0.f, 0.f};

    // prologue
#pragma unroll
    for (int r = 0; r < 4; ++r) breg[r] = *(const f32x4*)(wp + (size_t)r * Wld);
    {
        char* al = Asb[0] + tid * 16;
        gl_lds16(ag, al); gl_lds16(ag + r32K, al + 4096);
        gl_lds16(ag + 2 * r32K, al + 8192); gl_lds16(ag + 3 * r32K, al + 12288);
        ag += 64;
    }
#pragma unroll
    for (int j = 0; j < 4; ++j) {
        int n = nq * 4 + j;
        u32x2 v;
        v[0] = (unsigned int)f2bf(breg[0][j]) | ((unsigned int)f2bf(breg[1][j]) << 16);
        v[1] = (unsigned int)f2bf(breg[2][j]) | ((unsigned int)f2bf(breg[3][j]) << 16);
        *(u32x2*)(Bsb[0] + n * 128 + ((((kq >> 1) ^ (n & 7)) << 4)) + (kq & 1) * 8) = v;
    }

    for (int it = 0; it < nIter; ++it) {
        __syncthreads();
        if (it + 1 < nIter) {
            const float* p = wp + (size_t)(it + 1) * 64 * Wld;
#pragma unroll
            for (int r = 0; r < 4; ++r) breg[r] = *(const f32x4*)(p + (size_t)r * Wld);
            char* al = Asb[(it + 1) & 1] + tid * 16;
            gl_lds16(ag, al); gl_lds16(ag + r32K, al + 4096);
            gl_lds16(ag + 2 * r32K, al + 8192); gl_lds16(ag + 3 * r32K, al + 12288);
            ag += 64;
        }
        const char* Ab = Asb[it & 1];
        const char* Bb = Bsb[it & 1];
#pragma unroll
        for (int kk = 0; kk < 2; ++kk) {
            const int c = lhi + 4 * kk;
            short8 a[2], bv[4];
#pragma unroll
            for (int mi = 0; mi < 2; ++mi) {
                int ra = wid * 32 + mi * 16 + l15;
                a[mi] = *(const short8*)(Ab + ra * 128 + (((c ^ (ra & 7)) << 4)));
            }
#pragma unroll
            for (int ni = 0; ni < 4; ++ni) {
                int rb = ni * 16 + l15;
                bv[ni] = *(const short8*)(Bb + rb * 128 + (((c ^ (rb & 7)) << 4)));
            }
#pragma unroll
            for (int mi = 0; mi < 2; ++mi)
#pragma unroll
                for (int ni = 0; ni < 4; ++ni)
                    acc[mi][ni] = __builtin_amdgcn_mfma_f32_16x16x32_bf16(
                        a[mi], bv[ni], acc[mi][ni], 0, 0, 0);
        }
        if (it + 1 < nIter) {
            char* B = Bsb[(it + 1) & 1];
#pragma unroll
            for (int j = 0; j < 4; ++j) {
                int n = nq * 4 + j;
                u32x2 v;
                v[0] = (unsigned int)f2bf(breg[0][j]) | ((unsigned int)f2bf(breg[1][j]) << 16);
                v[1] = (unsigned int)f2bf(breg[2][j]) | ((unsigned int)f2bf(breg[3][j]) << 16);
                *(u32x2*)(B + n * 128 + ((((kq >> 1) ^ (n & 7)) << 4)) + (kq & 1) * 8) = v;
            }
        }
    }

#pragma unroll
    for (int mi = 0; mi < 2; ++mi)
#pragma unroll
        for (int ni = 0; ni < 4; ++ni) {
            int col = ocol0 + ni * 16 + l15;
            int rbase = row0 + wid * 32 + mi * 16 + lhi * 4;
            float cbv = cb ? cb[col] : 0.0f;
            f32x4 v = acc[mi][ni];
#pragma unroll
            for (int r = 0; r < 4; ++r)
                out[(size_t)(rbase + r) * ldo + col] = __float2bfloat16(v[r] + cbv);
        }
}

// ---------------------------------------------------------------------------
// Hoisted S-GEMMs: 16 AdaLN groups + 4 sgate groups, one dispatch.
// ---------------------------------------------------------------------------
struct HoistArgs {
    const __hip_bfloat16* snb; const __hip_bfloat16* S_bf;
    const float* a1sw; const float* a1shw; const float* a2sw; const float* a2shw;
    const float* sg_w; const float* tsg_w;
    const float* a1sb; const float* a2sb; const float* sgbias;
    __hip_bfloat16* SIG; __hip_bfloat16* SH; __hip_bfloat16* sgateb;
};

__global__ __launch_bounds__(256)
void gemmh_kernel(HoistArgs ha) {
    __shared__ __align__(16) char As[2][16384];
    __shared__ __align__(16) char Bs[2][8192];
    int b = blockIdx.x;
    if (b < 1536) {
        int z = b / 96, rem = b % 96;
        int y = rem / 12, x = rem % 12;
        int j = z & 7, half = z >> 3;
        const __hip_bfloat16* A = ha.snb + (size_t)j * NTOK * CS;
        const float* W = (half ? ((j & 1) ? ha.a2shw : ha.a1shw)
                               : ((j & 1) ? ha.a2sw : ha.a1sw)) + (size_t)(j >> 1) * CS * CT;
        const float* cb = half ? nullptr : (((j & 1) ? ha.a2sb : ha.a1sb) + (j >> 1) * CT);
        __hip_bfloat16* out = (half ? ha.SH : ha.SIG) + (size_t)j * NTOK * CT;
        wide_body(A, CS, W, CT, cb, out, 768, y * 128, x * 64, x * 64,
                  As[0], As[1], Bs[0], Bs[1]);
    } else {
        int b2 = b - 1536;
        int z = b2 / 192, rem = b2 % 192;
        int y = rem / 24, x = rem % 24;
        const float* W = ((x < 12) ? ha.sg_w : ha.tsg_w) + (size_t)z * CS * CT;
        int wcol0 = (x < 12) ? x * 64 : (x - 12) * 64;
        wide_body(ha.S_bf, CS, W, CT, ha.sgbias + z * 1536,
                  ha.sgateb + (size_t)z * NTOK * 1536, 1536,
                  y * 128, wcol0, x * 64, As[0], As[1], Bs[0], Bs[1]);
    }
}

// ---------------------------------------------------------------------------
// QKVG GEMM: grid (48,8); 4-matrix pointer table.
// ---------------------------------------------------------------------------
struct QkvgArgs {
    const __hip_bfloat16* an;
    const float* Wt[4];
    const float* cb;         // qkvgbias + i*3072 (global out col index)
    __hip_bfloat16* qkvg;
};

__global__ __launch_bounds__(256)
void gemmq_kernel(QkvgArgs qa) {
    __shared__ __align__(16) char As[2][16384];
    __shared__ __align__(16) char Bs[2][8192];
    int x = blockIdx.x, y = blockIdx.y;
    int sel = x / 12;
    wide_body(qa.an, CT, qa.Wt[sel], CT, qa.cb, qa.qkvg, 3072,
              y * 128, (x % 12) * 64, x * 64, As[0], As[1], Bs[0], Bs[1]);
}

// ---------------------------------------------------------------------------
// Narrow GEMM body: 64x64 tile, BK=64, 4 waves (2x2). fp32 W staging.
// DUAL: two W matrices, out = bf16(silu(acc1)*acc2).
// else: atomicAdd(outf, sigmoid(auxb)*acc1) (split-K residual).
// ---------------------------------------------------------------------------
template <bool DUAL>
__device__ __forceinline__ void nar_body(
    const __hip_bfloat16* A, int Kfull, int Ksub, int koff,
    const float* W1, const float* W2, int Wld,
    const __hip_bfloat16* auxb, int ld_aux,
    float* outf, __hip_bfloat16* outb, int ldo,
    int row0, int col0,
    char* As0, char* As1, char* B10, char* B11, char* B20, char* B21) {
    const int tid = threadIdx.x;
    const int lane = tid & 63;
    const int wid = tid >> 6;
    const int wr = wid >> 1, wc = wid & 1;
    char* Asb[2] = {As0, As1};
    char* B1b[2] = {B10, B11};
    char* B2b[2] = {B20, B21};

    const int srow = tid >> 3;
    const int sg_e = (((tid & 7) ^ (srow & 7)) << 3);
    const __hip_bfloat16* ag = A + (size_t)(row0 + srow) * Kfull + koff + sg_e;
    const size_t r32K = (size_t)32 * Kfull;

    const int kq = tid >> 4;
    const int nq = tid & 15;
    const float* wp1 = W1 + (size_t)(koff + kq * 4) * Wld + col0 + nq * 4;
    const float* wp2 = DUAL ? (W2 + (size_t)(koff + kq * 4) * Wld + col0 + nq * 4) : nullptr;
    f32x4 b1reg[4], b2reg[4];

    auto BLOAD = [&](int it) {
        const float* p1 = wp1 + (size_t)it * 64 * Wld;
#pragma unroll
        for (int r = 0; r < 4; ++r) b1reg[r] = *(const f32x4*)(p1 + (size_t)r * Wld);
        if (DUAL) {
            const float* p2 = wp2 + (size_t)it * 64 * Wld;
#pragma unroll
            for (int r = 0; r < 4; ++r) b2reg[r] = *(const f32x4*)(p2 + (size_t)r * Wld);
        }
    };
    auto BWRITE = [&](int bi) {
#pragma unroll
        for (int j = 0; j < 4; ++j) {
            int n = nq * 4 + j;
            int boff = n * 128 + ((((kq >> 1) ^ (n & 7)) << 4)) + (kq & 1) * 8;
            u32x2 v;
            v[0] = (unsigned int)f2bf(b1reg[0][j]) | ((unsigned int)f2bf(b1reg[1][j]) << 16);
            v[1] = (unsigned int)f2bf(b1reg[2][j]) | ((unsigned int)f2bf(b1reg[3][j]) << 16);
            *(u32x2*)(B1b[bi] + boff) = v;
            if (DUAL) {
                u32x2 w;
                w[0] = (unsigned int)f2bf(b2reg[0][j]) | ((unsigned int)f2bf(b2reg[1][j]) << 16);
                w[1] = (unsigned int)f2bf(b2reg[2][j]) | ((unsigned int)f2bf(b2reg[3][j]) << 16);
                *(u32x2*)(B2b[bi] + boff) = w;
            }
        }
    };
    auto ASTAGE = [&](int bi) {
        gl_lds16(ag, Asb[bi] + tid * 16);
        gl_lds16(ag + r32K, Asb[bi] + 4096 + tid * 16);
        ag += 64;
    };

    f32x4 acc[2][2];
    f32x4 acc2[2][2];
#pragma unroll
    for (int i = 0; i < 2; ++i)
#pragma unroll
        for (int j = 0; j < 2; ++j) {
            acc[i][j] = (f32x4){0.f, 0.f, 0.f, 0.f};
            acc2[i][j] = (f32x4){0.f, 0.f, 0.f, 0.f};
        }

    const int l15 = lane & 15;
    const int lhi = lane >> 4;
    const int nIter = Ksub >> 6;

    BLOAD(0); ASTAGE(0); BWRITE(0);
    for (int it = 0; it < nIter; ++it) {
        __syncthreads();
        if (it + 1 < nIter) { BLOAD(it + 1); ASTAGE((it + 1) & 1); }
        const char* Ab = Asb[it & 1];
        const char* Bb = B1b[it & 1];
        const char* Cb = DUAL ? B2b[it & 1] : nullptr;
#pragma unroll
        for (int kk = 0; kk < 2; ++kk) {
            const int c = lhi + 4 * kk;
            const int ra0 = wr * 32 + l15, ra1 = ra0 + 16;
            const int rb0 = wc * 32 + l15, rb1 = rb0 + 16;
            short8 a0 = *(const short8*)(Ab + ra0 * 128 + (((c ^ (ra0 & 7)) << 4)));
            short8 a1 = *(const short8*)(Ab + ra1 * 128 + (((c ^ (ra1 & 7)) << 4)));
            short8 b0 = *(const short8*)(Bb + rb0 * 128 + (((c ^ (rb0 & 7)) << 4)));
            short8 b1 = *(const short8*)(Bb + rb1 * 128 + (((c ^ (rb1 & 7)) << 4)));
            acc[0][0] = __builtin_amdgcn_mfma_f32_16x16x32_bf16(a0, b0, acc[0][0], 0, 0, 0);
            acc[0][1] = __builtin_amdgcn_mfma_f32_16x16x32_bf16(a0, b1, acc[0][1], 0, 0, 0);
            acc[1][0] = __builtin_amdgcn_mfma_f32_16x16x32_bf16(a1, b0, acc[1][0], 0, 0, 0);
            acc[1][1] = __builtin_amdgcn_mfma_f32_16x16x32_bf16(a1, b1, acc[1][1], 0, 0, 0);
            if (DUAL) {
                short8 c0 = *(const short8*)(Cb + rb0 * 128 + (((c ^ (rb0 & 7)) << 4)));
                short8 c1 = *(const short8*)(Cb + rb1 * 128 + (((c ^ (rb1 & 7)) << 4)));
                acc2[0][0] = __builtin_amdgcn_mfma_f32_16x16x32_bf16(a0, c0, acc2[0][0], 0, 0, 0);
                acc2[0][1] = __builtin_amdgcn_mfma_f32_16x16x32_bf16(a0, c1, acc2[0][1], 0, 0, 0);
                acc2[1][0] = __builtin_amdgcn_mfma_f32_16x16x32_bf16(a1, c0, acc2[1][0], 0, 0, 0);
                acc2[1][1] = __builtin_amdgcn_mfma_f32_16x16x32_bf16(a1, c1, acc2[1][1], 0, 0, 0);
            }
        }
        if (it + 1 < nIter) BWRITE((it + 1) & 1);
    }

#pragma unroll
    for (int mi = 0; mi < 2; ++mi)
#pragma unroll
        for (int ni = 0; ni < 2; ++ni) {
            f32x4 v1 = acc[mi][ni];
            f32x4 v2 = acc2[mi][ni];
            int col = col0 + wc * 32 + ni * 16 + l15;
            int rbase = row0 + wr * 32 + mi * 16 + lhi * 4;
#pragma unroll
            for (int r = 0; r < 4; ++r) {
                int row = rbase + r;
                size_t o = (size_t)row * ldo + col;
                if (DUAL) {
                    float x = v1[r];
                    outb[o] = __float2bfloat16(x * sigmoidf_(x) * v2[r]);
                } else {
                    float g = sigmoidf_(__bfloat162float(auxb[(size_t)row * ld_aux + col]));
                    atomicAdd(&outf[o], g * v1[r]);
                }
            }
        }
}

// SwiGLU transition: dual-B, grid (24,16)
__global__ __launch_bounds__(256)
void gemmd_kernel(const __hip_bfloat16* an, const float* W1, const float* W2,
                  __hip_bfloat16* hb) {
    __shared__ __align__(16) char As[2][8192];
    __shared__ __align__(16) char B1[2][8192];
    __shared__ __align__(16) char B2[2][8192];
    nar_body<true>(an, CT, CT, 0, W1, W2, 1536, nullptr, 0, nullptr, hb, 1536,
                   blockIdx.y * 64, blockIdx.x * 64,
                   As[0], As[1], B1[0], B1[1], B2[0], B2[1]);
}

// Gated residual: split-K z, grid (12,16,2)
__global__ __launch_bounds__(256)
void gemmr_kernel(const __hip_bfloat16* Ain, const float* W,
                  const __hip_bfloat16* auxb, float* Aout,
                  int Kfull, int Ksub) {
    __shared__ __align__(16) char As[2][8192];
    __shared__ __align__(16) char B1[2][8192];
    nar_body<false>(Ain, Kfull, Ksub, blockIdx.z * Ksub, W, nullptr, 768,
                    auxb, 1536, Aout, nullptr, 768,
                    blockIdx.y * 64, blockIdx.x * 64,
                    As[0], As[1], B1[0], B1[1], nullptr, nullptr);
}

// ---------------------------------------------------------------------------
// Attention + fused pair bias (unchanged from R13).
// ---------------------------------------------------------------------------
__global__ __launch_bounds__(256)
void attn_kernel(const __hip_bfloat16* __restrict__ qkvg,
                 const float* __restrict__ Z,
                 const int* __restrict__ idx,
                 const float* __restrict__ pg, const float* __restrict__ pb,
                 const float* __restrict__ Wbp,
                 __hip_bfloat16* __restrict__ o2) {
    int n = blockIdx.x;
    int t = threadIdx.x;
    __shared__ __align__(16) unsigned short qs[768];
    __shared__ float sc[16][48];
    __shared__ float lnz[KTOT][16];
    __shared__ float wb[16][17];
    __shared__ float pgs[16], pbs[16];
    __shared__ int sidx[KTOT];
    __shared__ float pacc[96][8];

    wb[t >> 4][t & 15] = Wbp[t];
    if (t < 96) ((short8*)qs)[t] = ((const short8*)(qkvg + (size_t)n * 3072))[t];
    if (t >= 96 && t < 96 + KTOT) sidx[t - 96] = idx[n * KTOT + (t - 96)];
    if (t >= 160 && t < 176) pgs[t - 160] = pg[t - 160];
    if (t >= 176 && t < 192) pbs[t - 176] = pb[t - 176];
    __syncthreads();

    if (t < KTOT) {
        const f32x4* z = (const f32x4*)(Z + ((size_t)n * NTOK + sidx[t]) * CP);
        f32x4 z0 = z[0], z1 = z[1], z2 = z[2], z3 = z[3];
        float v[16];
#pragma unroll
        for (int e = 0; e < 4; ++e) { v[e] = z0[e]; v[4 + e] = z1[e]; v[8 + e] = z2[e]; v[12 + e] = z3[e]; }
        float s = 0.0f;
#pragma unroll
        for (int c = 0; c < 16; ++c) s += v[c];
        float mean = s * (1.0f / 16.0f);
        float s2 = 0.0f;
#pragma unroll
        for (int c = 0; c < 16; ++c) { float d = v[c] - mean; s2 += d * d; }
        float rstd = rsqrtf(s2 * (1.0f / 16.0f) + 1e-5f);
#pragma unroll
        for (int c = 0; c < 16; ++c) lnz[t][c] = (v[c] - mean) * rstd * pgs[c] + pbs[c];
    }
    __syncthreads();

    for (int task = t; task < NH * KTOT; task += 256) {
        int h = task / KTOT, k = task - h * KTOT;
        const short8* kp = (const short8*)((const unsigned short*)qkvg +
                                           (size_t)sidx[k] * 3072 + 768 + h * DH);
        const short8* qp = (const short8*)(qs + h * DH);
        float s = 0.0f;
#pragma unroll
        for (int j = 0; j < 6; ++j) {
            short8 kv = kp[j];
            short8 qv = qp[j];
#pragma unroll
            for (int e = 0; e < 8; ++e)
                s += bf2f((unsigned short)qv[e]) * bf2f((unsigned short)kv[e]);
        }
        float bias = 0.0f;
#pragma unroll
        for (int c = 0; c < 16; ++c) bias += lnz[k][c] * wb[c][h];
        sc[h][k] = s * SCALE_ + bias;
    }
    __syncthreads();

    {
        int h = t >> 4, l = t & 15;
        float v0 = sc[h][l];
        float v1 = sc[h][l + 16];
        float v2 = (l < 8) ? sc[h][l + 32] : -INFINITY;
        float mx = fmaxf(fmaxf(v0, v1), v2);
#pragma unroll
        for (int m = 8; m > 0; m >>= 1) mx = fmaxf(mx, __shfl_xor(mx, m, 16));
        float e0 = __expf(v0 - mx), e1 = __expf(v1 - mx);
        float e2 = (l < 8) ? __expf(v2 - mx) : 0.0f;
        float sm = e0 + e1 + e2;
#pragma unroll
        for (int m = 8; m > 0; m >>= 1) sm += __shfl_xor(sm, m, 16);
        float inv = 1.0f / sm;
        sc[h][l] = e0 * inv;
        sc[h][l + 16] = e1 * inv;
        if (l < 8) sc[h][l + 32] = e2 * inv;
    }
    __syncthreads();

    float acc[8] = {0, 0, 0, 0, 0, 0, 0, 0};
    const int half = (t >= 96) ? 1 : 0;
    const int tt = t - half * 96;
    if (t < 192) {
        int h = tt / 6, c6 = tt - h * 6;
        int d0 = c6 * 8;
        const unsigned short* vbase = (const unsigned short*)qkvg + 1536 + h * DH + d0;
        for (int k = half * 20; k < half * 20 + 20; ++k) {
            short8 vv = *(const short8*)(vbase + (size_t)sidx[k] * 3072);
            float w = sc[h][k];
#pragma unroll
            for (int e = 0; e < 8; ++e) acc[e] += w * bf2f((unsigned short)vv[e]);
        }
    }
    if (half && t < 192) {
#pragma unroll
        for (int e = 0; e < 8; ++e) pacc[tt][e] = acc[e];
    }
    __syncthreads();
    if (t < 96) {
        int h = t / 6, c6 = t - h * 6;
        int d0 = c6 * 8;
        short8 gv = *(const short8*)((const unsigned short*)qkvg +
                                     (size_t)n * 3072 + 2304 + h * DH + d0);
        short8 ov;
#pragma unroll
        for (int e = 0; e < 8; ++e) {
            float g = sigmoidf_(bf2f((unsigned short)gv[e]));
            ov[e] = (short)f2bf(g * (acc[e] + pacc[t][e]));
        }
        *(short8*)((unsigned short*)o2 + (size_t)n * CT + h * DH + d0) = ov;
    }
}

// ---------------------------------------------------------------------------
// Host orchestration
// ---------------------------------------------------------------------------
extern "C" void kernel_launch(void* const* d_in, const int* in_sizes, int n_in,
                              void* d_out, int out_size, void* d_ws, size_t ws_size,
                              hipStream_t stream) {
    const float* A_I  = (const float*)d_in[0];
    const float* S_I  = (const float*)d_in[1];
    const float* Z_II = (const float*)d_in[2];
    const float* X_L  = (const float*)d_in[3];
    const float* aln1_sln_g = (const float*)d_in[5];
    const float* aln1_sw    = (const float*)d_in[6];
    const float* aln1_sb    = (const float*)d_in[7];
    const float* aln1_shw   = (const float*)d_in[8];
    const float* Wq  = (const float*)d_in[9];
    const float* bq  = (const float*)d_in[10];
    const float* Wk  = (const float*)d_in[11];
    const float* Wv  = (const float*)d_in[12];
    const float* pair_ln_g = (const float*)d_in[13];
    const float* pair_ln_b = (const float*)d_in[14];
    const float* Wbp = (const float*)d_in[15];
    const float* Wg  = (const float*)d_in[16];
    const float* Wo  = (const float*)d_in[17];
    const float* sg_w = (const float*)d_in[18];
    const float* sg_b = (const float*)d_in[19];
    const float* aln2_sln_g = (const float*)d_in[20];
    const float* aln2_sw    = (const float*)d_in[21];
    const float* aln2_sb    = (const float*)d_in[22];
    const float* aln2_shw   = (const float*)d_in[23];
    const float* t_w1 = (const float*)d_in[24];
    const float* t_w2 = (const float*)d_in[25];
    const float* t_w3 = (const float*)d_in[26];
    const float* tsg_w = (const float*)d_in[27];
    const float* tsg_b = (const float*)d_in[28];
    (void)in_sizes; (void)n_in; (void)out_size; (void)ws_size;

    float* A = (float*)d_out;

    char* ws = (char*)d_ws;
    size_t off = 0;
    auto alloc = [&](size_t bytes) {
        void* p = ws + off;
        off += (bytes + 255) & ~(size_t)255;
        return p;
    };
    int*   idx    = (int*)  alloc(NTOK * KTOT * 4);
    __hip_bfloat16* S_bf  = (__hip_bfloat16*)alloc((size_t)NTOK * CS * 2);
    __hip_bfloat16* snb   = (__hip_bfloat16*)alloc((size_t)8 * NTOK * CS * 2);
    __hip_bfloat16* an    = (__hip_bfloat16*)alloc((size_t)NTOK * CT * 2);
    __hip_bfloat16* qkvg  = (__hip_bfloat16*)alloc((size_t)NTOK * 3072 * 2);
    __hip_bfloat16* sgateb= (__hip_bfloat16*)alloc((size_t)NBLK * NTOK * 1536 * 2);
    __hip_bfloat16* SIG   = (__hip_bfloat16*)alloc((size_t)8 * NTOK * CT * 2);
    __hip_bfloat16* SH    = (__hip_bfloat16*)alloc((size_t)8 * NTOK * CT * 2);
    __hip_bfloat16* o2    = (__hip_bfloat16*)alloc((size_t)NTOK * CT * 2);
    __hip_bfloat16* hb    = (__hip_bfloat16*)alloc((size_t)NTOK * 2 * CT * 2);
    float* qkvgbias = (float*)alloc((size_t)NBLK * 3072 * 4);
    float* sgbias   = (float*)alloc((size_t)NBLK * 1536 * 4);

    hipMemcpyAsync(A, A_I, (size_t)NTOK * CT * 4, hipMemcpyDeviceToDevice, stream);

    // ---- prep ----
    {
        PrepArgs pa;
        pa.X_L = X_L; pa.idx = idx;
        pa.S = S_I; pa.g1 = aln1_sln_g; pa.g2 = aln2_sln_g;
        pa.S_bf = S_bf; pa.snb = snb;
        pa.bq = bq; pa.sg_b = sg_b; pa.tsg_b = tsg_b;
        pa.qb = qkvgbias; pa.sb2 = sgbias;
        prep_kernel<<<1328, 384, 0, stream>>>(pa);
    }

    // ---- hoisted S-GEMMs (fp32 weights, fused convert) ----
    {
        HoistArgs ha;
        ha.snb = snb; ha.S_bf = S_bf;
        ha.a1sw = aln1_sw; ha.a1shw = aln1_shw; ha.a2sw = aln2_sw; ha.a2shw = aln2_shw;
        ha.sg_w = sg_w; ha.tsg_w = tsg_w;
        ha.a1sb = aln1_sb; ha.a2sb = aln2_sb; ha.sgbias = sgbias;
        ha.SIG = SIG; ha.SH = SH; ha.sgateb = sgateb;
        gemmh_kernel<<<2304, 256, 0, stream>>>(ha);
    }

    for (int i = 0; i < NBLK; ++i) {
        __hip_bfloat16* sg_i = sgateb + (size_t)i * NTOK * 1536;

        // ---- LocalAttentionPairBias ----
        adaapply_kernel<<<NTOK, 256, 0, stream>>>(
            A, SIG + (size_t)(2 * i) * NTOK * CT, SH + (size_t)(2 * i) * NTOK * CT, an);
        {
            QkvgArgs qa;
            qa.an = an;
            qa.Wt[0] = Wq + (size_t)i * CT * CT;
            qa.Wt[1] = Wk + (size_t)i * CT * CT;
            qa.Wt[2] = Wv + (size_t)i * CT * CT;
            qa.Wt[3] = Wg + (size_t)i * CT * CT;
            qa.cb = qkvgbias + (size_t)i * 3072;
            qa.qkvg = qkvg;
            gemmq_kernel<<<dim3(48, 8), 256, 0, stream>>>(qa);
        }
        attn_kernel<<<NTOK, 256, 0, stream>>>(
            qkvg, Z_II, idx, pair_ln_g + (size_t)i * CP, pair_ln_b + (size_t)i * CP,
            Wbp + (size_t)i * CP * NH, o2);
        gemmr_kernel<<<dim3(12, 16, 2), 256, 0, stream>>>(
            o2, Wo + (size_t)i * CT * CT, sg_i, A, 768, 384);

        // ---- ConditionedTransitionBlock ----
        adaapply_kernel<<<NTOK, 256, 0, stream>>>(
            A, SIG + (size_t)(2 * i + 1) * NTOK * CT, SH + (size_t)(2 * i + 1) * NTOK * CT, an);
        gemmd_kernel<<<dim3(24, 16), 256, 0, stream>>>(
            an, t_w1 + (size_t)i * CT * 2 * CT, t_w2 + (size_t)i * CT * 2 * CT, hb);
        gemmr_kernel<<<dim3(12, 16, 2), 256, 0, stream>>>(
            hb, t_w3 + (size_t)i * 2 * CT * CT, sg_i + 768, A, 1536, 768);
    }
}

// Round 16
// 393.684 us; speedup vs baseline: 1.2935x; 1.2935x over previous
//
#include <hip/hip_runtime.h>
#include <hip/hip_bf16.h>
#include <math.h>
#include <stdint.h>

#define NTOK 1024
#define CT   768
#define CS   384
#define CP   16
#define NH   16
#define DH   48
#define NBLK 4
#define NL   8
#define NKEY 32
#define KTOT 40
#define SCALE_ 0.14433756729740643f   // 1/sqrt(48)

// Wbuf per-block element offsets (bf16 elements)
#define WS_BLK      8257536
#define OFF_A1SW    0
#define OFF_A1SHW   294912
#define OFF_QKVG    589824
#define OFF_WO      2949120
#define OFF_SGT     3538944
#define OFF_A2SW    4128768
#define OFF_A2SHW   4423680
#define OFF_TW1     4718592
#define OFF_TW2     5898240
#define OFF_TW3     7077888

#define NCONVT 504          // 128x128 conv tiles per weight-block
#define NPREPB 1328         // 256 topk + 1024 sprep + 48 biasprep

typedef __attribute__((ext_vector_type(8))) short short8;
typedef __attribute__((ext_vector_type(4))) float f32x4;

#define AS1 __attribute__((address_space(1)))
#define AS3 __attribute__((address_space(3)))

__device__ __forceinline__ float sigmoidf_(float x) {
    return 1.0f / (1.0f + __expf(-x));
}
__device__ __forceinline__ float bf2f(unsigned short u) {
    union { unsigned int i; float f; } v; v.i = (unsigned int)u << 16; return v.f;
}
__device__ __forceinline__ unsigned short f2bf(float f) {
    return __bfloat16_as_ushort(__float2bfloat16(f));
}

__device__ __forceinline__ void gl_lds16(const void* g, void* l) {
    __builtin_amdgcn_global_load_lds((const AS1 void*)(uintptr_t)g,
                                     (AS3 void*)(uintptr_t)l, 16, 0, 0);
}

// ---------------------------------------------------------------------------
// Merged conv+prep kernel. Blocks [0,1328): prep roles FIRST in launch order
// (long small blocks fill CUs, conv stream hides them). Blocks >= 1328:
// weight convert+transpose (in-register 8x8, no LDS).
// ---------------------------------------------------------------------------
struct ConvDesc { const float* src; __hip_bfloat16* dst; int K; int N; int tstart; int srcStride; };
struct ConvPrep {
    ConvDesc e[14];
    const float* X_L; int* idx;
    const float* S; const float* g1; const float* g2;
    __hip_bfloat16* S_bf; __hip_bfloat16* snb;
    const float* bq; const float* sg_b; const float* tsg_b;
    float* qb; float* sb2;
};

__global__ __launch_bounds__(256)
void convprep_kernel(ConvPrep pa) {
    __shared__ float ls[8];
    const int t = threadIdx.x;
    const int b = blockIdx.x;

    if (b >= NPREPB) {
        // ---- convT role ----
        int cb = b - NPREPB;
        int wblk = cb / NCONVT;
        int tt_all = cb % NCONVT;
        int ei = 0;
#pragma unroll
        for (int j = 1; j < 14; ++j) if (tt_all >= pa.e[j].tstart) ei = j;
        ConvDesc d = pa.e[ei];
        const float* src = d.src + (size_t)wblk * d.srcStride;
        unsigned short* dst = (unsigned short*)(d.dst + (size_t)wblk * WS_BLK);
        int tt = tt_all - d.tstart;
        int ntn = d.N / 128;
        int k0 = (tt / ntn) * 128, n0 = (tt % ntn) * 128;

        const int ck = t & 15;
        const int cn = t >> 4;
        const float* sp = src + (size_t)(k0 + ck * 8) * d.N + n0 + cn * 8;
        f32x4 va[8], vb[8];
#pragma unroll
        for (int r = 0; r < 8; ++r) {
            va[r] = *(const f32x4*)(sp + (size_t)r * d.N);
            vb[r] = *(const f32x4*)(sp + (size_t)r * d.N + 4);
        }
        unsigned short* dp = dst + (size_t)(n0 + cn * 8) * d.K + k0 + ck * 8;
#pragma unroll
        for (int j = 0; j < 8; ++j) {
            short8 o;
#pragma unroll
            for (int e = 0; e < 8; ++e) {
                float f = (j < 4) ? va[e][j] : vb[e][j - 4];
                o[e] = (short)f2bf(f);
            }
            *(short8*)(dp + (size_t)j * d.K) = o;
        }
        return;
    }

    if (b < 256) {
        // ---- topk: one wave per token ----
        const int w = t >> 6;
        const int l = t & 63;
        const int n = b * 4 + w;
        const float* X = pa.X_L;
        int* idx = pa.idx;

        const float x0 = X[n * 3 + 0], x1 = X[n * 3 + 1], x2 = X[n * 3 + 2];
        float d[16];
        unsigned long long lkey = ~0ull;
#pragma unroll
        for (int j = 0; j < 16; ++j) {
            int m = j * 64 + l;
            float dx = x0 - X[m * 3 + 0];
            float dy = x1 - X[m * 3 + 1];
            float dz = x2 - X[m * 3 + 2];
            float v = dx * dx + dy * dy + dz * dz;
            d[j] = v;
            unsigned long long key =
                ((unsigned long long)__float_as_uint(v) << 32) | (unsigned int)m;
            lkey = key < lkey ? key : lkey;
        }
        if (l < NL) {
            int loc = n + l - NL / 2;
            loc = loc < 0 ? 0 : (loc > NTOK - 1 ? NTOK - 1 : loc);
            idx[n * KTOT + l] = loc;
        }
        for (int it = 0; it < NKEY; ++it) {
            unsigned long long rk = lkey;
#pragma unroll
            for (int s = 32; s > 0; s >>= 1) {
                unsigned long long o = __shfl_xor(rk, s, 64);
                rk = o < rk ? o : rk;
            }
            unsigned int win = (unsigned int)rk;
            if (l == 0) idx[n * KTOT + NL + it] = (int)win;
            if ((int)(win & 63) == l) {
                int jw = (int)(win >> 6);
                unsigned long long nk = ~0ull;
#pragma unroll
                for (int j = 0; j < 16; ++j) {
                    if (j == jw) d[j] = INFINITY;
                    unsigned long long key =
                        ((unsigned long long)__float_as_uint(d[j]) << 32) |
                        (unsigned int)(j * 64 + l);
                    nk = key < nk ? key : nk;
                }
                lkey = nk;
            }
        }
        return;
    }

    if (b < 1280) {
        // ---- sprep (256 threads, 384 cols) ----
        int r = b - 256;
        int wid = t >> 6, l = t & 63;
        const float* S = pa.S;
        float v0 = S[r * CS + t];
        float v1 = (t < 128) ? S[r * CS + 256 + t] : 0.0f;
        float s = v0 + v1;
#pragma unroll
        for (int m = 32; m > 0; m >>= 1) s += __shfl_xor(s, m, 64);
        if (l == 0) ls[wid] = s;
        __syncthreads();
        float mean = (ls[0] + ls[1] + ls[2] + ls[3]) * (1.0f / CS);
        float d0 = v0 - mean, d1 = v1 - mean;
        float q = d0 * d0 + ((t < 128) ? d1 * d1 : 0.0f);
#pragma unroll
        for (int m = 32; m > 0; m >>= 1) q += __shfl_xor(q, m, 64);
        if (l == 0) ls[4 + wid] = q;
        __syncthreads();
        float rstd = rsqrtf((ls[4] + ls[5] + ls[6] + ls[7]) * (1.0f / CS) + 1e-5f);
        float ln0 = d0 * rstd, ln1 = d1 * rstd;
        pa.S_bf[r * CS + t] = __float2bfloat16(v0);
        if (t < 128) pa.S_bf[r * CS + 256 + t] = __float2bfloat16(v1);
#pragma unroll
        for (int j = 0; j < 8; ++j) {
            const float* g = ((j & 1) ? pa.g2 : pa.g1) + (j >> 1) * CS;
            size_t base = ((size_t)j * NTOK + r) * CS;
            pa.snb[base + t] = __float2bfloat16(ln0 * g[t]);
            if (t < 128) pa.snb[base + 256 + t] = __float2bfloat16(ln1 * g[256 + t]);
        }
        return;
    }

    // ---- biasprep ----
    {
        int tt = (b - 1280) * 256 + t;
        if (tt < NBLK * 3072) {
            int i = tt / 3072, c = tt % 3072;
            pa.qb[tt] = (c < 768) ? pa.bq[i * 768 + c] : 0.0f;
        }
        if (tt < NBLK * 1536) {
            int i = tt / 1536, c = tt % 1536;
            pa.sb2[tt] = (c < 768) ? pa.sg_b[i * 768 + c] : pa.tsg_b[i * 768 + c - 768];
        }
    }
}

// ---------------------------------------------------------------------------
// AdaLN apply: an = bf16( sigmoid(SIG) * LN(A) + SH ). One block per row.
// ---------------------------------------------------------------------------
__global__ __launch_bounds__(256)
void adaapply_kernel(const float* __restrict__ A,
                     const __hip_bfloat16* __restrict__ SIG,
                     const __hip_bfloat16* __restrict__ SH,
                     __hip_bfloat16* __restrict__ an) {
    int r = blockIdx.x, t = threadIdx.x;
    int wid = t >> 6, l = t & 63;
    __shared__ float ls[8];
    const float* ar = A + (size_t)r * CT;
    float v0 = ar[t], v1 = ar[t + 256], v2 = ar[t + 512];
    float s = v0 + v1 + v2;
#pragma unroll
    for (int m = 32; m > 0; m >>= 1) s += __shfl_xor(s, m, 64);
    if (l == 0) ls[wid] = s;
    __syncthreads();
    float mean = (ls[0] + ls[1] + ls[2] + ls[3]) * (1.0f / CT);
    float d0 = v0 - mean, d1 = v1 - mean, d2 = v2 - mean;
    float q = d0 * d0 + d1 * d1 + d2 * d2;
#pragma unroll
    for (int m = 32; m > 0; m >>= 1) q += __shfl_xor(q, m, 64);
    if (l == 0) ls[4 + wid] = q;
    __syncthreads();
    float rstd = rsqrtf((ls[4] + ls[5] + ls[6] + ls[7]) * (1.0f / CT) + 1e-5f);
    size_t base = (size_t)r * CT;
    float dd[3] = {d0, d1, d2};
#pragma unroll
    for (int k = 0; k < 3; ++k) {
        int c = t + k * 256;
        float sg = sigmoidf_(__bfloat162float(SIG[base + c]));
        float sh = __bfloat162float(SH[base + c]);
        an[base + c] = __float2bfloat16(sg * dd[k] * rstd + sh);
    }
}

// ---------------------------------------------------------------------------
// Merged hoisted S-GEMMs: AdaLN pre (16 groups, blocks<1536) + sgate pre
// (4 groups). Wide tile 128x64, BK=64, dbuf single-barrier, K=384.
// ---------------------------------------------------------------------------
struct HoistArgs {
    const __hip_bfloat16* snb; const __hip_bfloat16* S_bf;
    const __hip_bfloat16* Wbuf;
    const float* a1sb; const float* a2sb; const float* sgbias;
    __hip_bfloat16* SIG; __hip_bfloat16* SH; __hip_bfloat16* sgateb;
};

__device__ __forceinline__ void wide_body(
    const __hip_bfloat16* A, const __hip_bfloat16* B1, const float* cb,
    __hip_bfloat16* outp, int K, int ldo, int row0, int col0,
    char (*As)[16384], char (*Bs)[8192]) {
    const int tid = threadIdx.x;
    const int lane = tid & 63;
    const int wid = tid >> 6;
    const int srow = tid >> 3;
    const int sg_e = (((tid & 7) ^ (srow & 7)) << 3);
    const __hip_bfloat16* ag = A + (size_t)(row0 + srow) * K + sg_e;
    const __hip_bfloat16* bg = B1 + (size_t)(col0 + srow) * K + sg_e;
    const size_t r32K = (size_t)32 * K;
    f32x4 acc[2][4];
#pragma unroll
    for (int i = 0; i < 2; ++i)
#pragma unroll
        for (int jj = 0; jj < 4; ++jj) acc[i][jj] = (f32x4){0.f, 0.f, 0.f, 0.f};
    const int l15 = lane & 15;
    const int lhi = lane >> 4;
    const int nIter = K >> 6;
    auto STAGE = [&](int bi) {
        char* al = As[bi] + tid * 16;
        char* bl = Bs[bi] + tid * 16;
        gl_lds16(ag, al);
        gl_lds16(ag + r32K, al + 4096);
        gl_lds16(ag + 2 * r32K, al + 8192);
        gl_lds16(ag + 3 * r32K, al + 12288);
        gl_lds16(bg, bl);
        gl_lds16(bg + r32K, bl + 4096);
        ag += 64; bg += 64;
    };
    STAGE(0);
    for (int it = 0; it < nIter; ++it) {
        __syncthreads();
        if (it + 1 < nIter) STAGE((it + 1) & 1);
        const char* Ab = As[it & 1];
        const char* Bb = Bs[it & 1];
#pragma unroll
        for (int kk = 0; kk < 2; ++kk) {
            const int c = lhi + 4 * kk;
            short8 a[2], bv[4];
#pragma unroll
            for (int mi = 0; mi < 2; ++mi) {
                int ra = wid * 32 + mi * 16 + l15;
                a[mi] = *(const short8*)(Ab + ra * 128 + (((c ^ (ra & 7)) << 4)));
            }
#pragma unroll
            for (int ni = 0; ni < 4; ++ni) {
                int rb = ni * 16 + l15;
                bv[ni] = *(const short8*)(Bb + rb * 128 + (((c ^ (rb & 7)) << 4)));
            }
#pragma unroll
            for (int mi = 0; mi < 2; ++mi)
#pragma unroll
                for (int ni = 0; ni < 4; ++ni)
                    acc[mi][ni] = __builtin_amdgcn_mfma_f32_16x16x32_bf16(
                        a[mi], bv[ni], acc[mi][ni], 0, 0, 0);
        }
    }
#pragma unroll
    for (int mi = 0; mi < 2; ++mi)
#pragma unroll
        for (int ni = 0; ni < 4; ++ni) {
            int col = col0 + ni * 16 + l15;
            int rbase = row0 + wid * 32 + mi * 16 + lhi * 4;
            float cbv = cb ? cb[col] : 0.0f;
            f32x4 v = acc[mi][ni];
#pragma unroll
            for (int r = 0; r < 4; ++r)
                outp[(size_t)(rbase + r) * ldo + col] = __float2bfloat16(v[r] + cbv);
        }
}

__global__ __launch_bounds__(256)
void gemmh_kernel(HoistArgs ha) {
    __shared__ __align__(16) char As[2][16384];
    __shared__ __align__(16) char Bs[2][8192];
    int b = blockIdx.x;
    if (b < 1536) {
        int z = b / 96, rem = b % 96;
        int y = rem / 12, x = rem % 12;
        int j = z & 7, half = z >> 3;
        const __hip_bfloat16* A = ha.snb + (size_t)j * NTOK * CS;
        const __hip_bfloat16* B1 = ha.Wbuf + (size_t)(j >> 1) * WS_BLK
            + ((j & 1) ? OFF_A2SW : OFF_A1SW)
            + (size_t)half * (OFF_A1SHW - OFF_A1SW);
        const float* cb = half ? nullptr : (((j & 1) ? ha.a2sb : ha.a1sb) + (j >> 1) * CT);
        __hip_bfloat16* outp = (half ? ha.SH : ha.SIG) + (size_t)j * NTOK * CT;
        wide_body(A, B1, cb, outp, CS, 768, y * 128, x * 64, As, Bs);
    } else {
        int b2 = b - 1536;
        int z = b2 / 192, rem = b2 % 192;
        int y = rem / 24, x = rem % 24;
        const __hip_bfloat16* B1 = ha.Wbuf + OFF_SGT + (size_t)z * WS_BLK;
        wide_body(ha.S_bf, B1, ha.sgbias + z * 1536,
                  ha.sgateb + (size_t)z * NTOK * 1536, CS, 1536,
                  y * 128, x * 64, As, Bs);
    }
}

// ---------------------------------------------------------------------------
// Wide bf16 MFMA GEMM 128x64 (QKVG). Dbuf single-barrier.
// ---------------------------------------------------------------------------
__global__ __launch_bounds__(256)
void gemmw_kernel(const __hip_bfloat16* A, const __hip_bfloat16* B1,
                  const float* cb, __hip_bfloat16* outb,
                  int K, int N, int ldo) {
    __shared__ __align__(16) char As[2][16384];
    __shared__ __align__(16) char Bs[2][8192];
    wide_body(A, B1, cb, outb, K, ldo, blockIdx.y * 128, blockIdx.x * 64, As, Bs);
}

// ---------------------------------------------------------------------------
// 64x64 GEMM, dbuf single-barrier.
// MODE 2: outb = bf16( silu(acc1) * acc2 )    (dual B)
// MODE 3: atomicAdd(outf, sigmoid(auxb)*acc1) (gated residual, split-K z=4)
// ---------------------------------------------------------------------------
template <int MODE>
__global__ __launch_bounds__(256)
void gemm_kernel(const __hip_bfloat16* __restrict__ A,
                 const __hip_bfloat16* B1,
                 const __hip_bfloat16* B2,
                 const __hip_bfloat16* __restrict__ auxb, int ld_aux,
                 float* __restrict__ outf,
                 __hip_bfloat16* outb,
                 int Kfull, int Ksub, int N, int ldo) {
    constexpr bool DUAL = (MODE == 2);
    __shared__ __align__(16) char As[2][8192];
    __shared__ __align__(16) char Bs[2][8192];
    __shared__ __align__(16) char Bs2[DUAL ? 2 : 1][DUAL ? 8192 : 16];

    const int tid = threadIdx.x;
    const int lane = tid & 63;
    const int wid = tid >> 6;
    const int wr = wid >> 1, wc = wid & 1;
    const int row0 = blockIdx.y * 64;
    const int col0 = blockIdx.x * 64;
    const int koff = blockIdx.z * Ksub;

    const int srow = tid >> 3;
    const int sg_e = (((tid & 7) ^ (srow & 7)) << 3);
    const __hip_bfloat16* ag = A + (size_t)(row0 + srow) * Kfull + koff + sg_e;
    const __hip_bfloat16* bg = B1 + (size_t)(col0 + srow) * Kfull + koff + sg_e;
    const __hip_bfloat16* bg2 = DUAL ? (B2 + (size_t)(col0 + srow) * Kfull + koff + sg_e) : nullptr;
    const size_t r32K = (size_t)32 * Kfull;

    auto STAGE = [&](int bi) {
        gl_lds16(ag, As[bi] + tid * 16);
        gl_lds16(ag + r32K, As[bi] + 4096 + tid * 16);
        gl_lds16(bg, Bs[bi] + tid * 16);
        gl_lds16(bg + r32K, Bs[bi] + 4096 + tid * 16);
        if (DUAL) {
            gl_lds16(bg2, Bs2[bi] + tid * 16);
            gl_lds16(bg2 + r32K, Bs2[bi] + 4096 + tid * 16);
            bg2 += 64;
        }
        ag += 64; bg += 64;
    };

    f32x4 acc[2][2];
    f32x4 acc2[2][2];
#pragma unroll
    for (int i = 0; i < 2; ++i)
#pragma unroll
        for (int j = 0; j < 2; ++j) {
            acc[i][j] = (f32x4){0.f, 0.f, 0.f, 0.f};
            acc2[i][j] = (f32x4){0.f, 0.f, 0.f, 0.f};
        }

    const int l15 = lane & 15;
    const int lhi = lane >> 4;
    const int nIter = Ksub >> 6;

    STAGE(0);
    for (int it = 0; it < nIter; ++it) {
        __syncthreads();
        if (it + 1 < nIter) STAGE((it + 1) & 1);
        const char* Ab = As[it & 1];
        const char* Bb = Bs[it & 1];
        const char* Cb = DUAL ? Bs2[it & 1] : nullptr;
#pragma unroll
        for (int kk = 0; kk < 2; ++kk) {
            const int c = lhi + 4 * kk;
            const int ra0 = wr * 32 + l15, ra1 = ra0 + 16;
            const int rb0 = wc * 32 + l15, rb1 = rb0 + 16;
            short8 a0 = *(const short8*)(Ab + ra0 * 128 + (((c ^ (ra0 & 7)) << 4)));
            short8 a1 = *(const short8*)(Ab + ra1 * 128 + (((c ^ (ra1 & 7)) << 4)));
            short8 b0 = *(const short8*)(Bb + rb0 * 128 + (((c ^ (rb0 & 7)) << 4)));
            short8 b1 = *(const short8*)(Bb + rb1 * 128 + (((c ^ (rb1 & 7)) << 4)));
            acc[0][0] = __builtin_amdgcn_mfma_f32_16x16x32_bf16(a0, b0, acc[0][0], 0, 0, 0);
            acc[0][1] = __builtin_amdgcn_mfma_f32_16x16x32_bf16(a0, b1, acc[0][1], 0, 0, 0);
            acc[1][0] = __builtin_amdgcn_mfma_f32_16x16x32_bf16(a1, b0, acc[1][0], 0, 0, 0);
            acc[1][1] = __builtin_amdgcn_mfma_f32_16x16x32_bf16(a1, b1, acc[1][1], 0, 0, 0);
            if (DUAL) {
                short8 c0 = *(const short8*)(Cb + rb0 * 128 + (((c ^ (rb0 & 7)) << 4)));
                short8 c1 = *(const short8*)(Cb + rb1 * 128 + (((c ^ (rb1 & 7)) << 4)));
                acc2[0][0] = __builtin_amdgcn_mfma_f32_16x16x32_bf16(a0, c0, acc2[0][0], 0, 0, 0);
                acc2[0][1] = __builtin_amdgcn_mfma_f32_16x16x32_bf16(a0, c1, acc2[0][1], 0, 0, 0);
                acc2[1][0] = __builtin_amdgcn_mfma_f32_16x16x32_bf16(a1, c0, acc2[1][0], 0, 0, 0);
                acc2[1][1] = __builtin_amdgcn_mfma_f32_16x16x32_bf16(a1, c1, acc2[1][1], 0, 0, 0);
            }
        }
    }

#pragma unroll
    for (int mi = 0; mi < 2; ++mi)
#pragma unroll
        for (int ni = 0; ni < 2; ++ni) {
            f32x4 v1 = acc[mi][ni];
            f32x4 v2 = acc2[mi][ni];
            int col = col0 + wc * 32 + ni * 16 + l15;
            int rbase = row0 + wr * 32 + mi * 16 + lhi * 4;
#pragma unroll
            for (int r = 0; r < 4; ++r) {
                int row = rbase + r;
                size_t o = (size_t)row * ldo + col;
                if (MODE == 2) {
                    float x = v1[r];
                    outb[o] = __float2bfloat16(x * sigmoidf_(x) * v2[r]);
                } else {
                    float g = sigmoidf_(__bfloat162float(auxb[(size_t)row * ld_aux + col]));
                    atomicAdd(&outf[o], g * v1[r]);
                }
            }
        }
}

// ---------------------------------------------------------------------------
// Attention + fused pair bias. One block per token. bf16 qkvg [1024][3072].
// ---------------------------------------------------------------------------
__global__ __launch_bounds__(256)
void attn_kernel(const __hip_bfloat16* __restrict__ qkvg,
                 const float* __restrict__ Z,
                 const int* __restrict__ idx,
                 const float* __restrict__ pg, const float* __restrict__ pb,
                 const float* __restrict__ Wbp,
                 __hip_bfloat16* __restrict__ o2) {
    int n = blockIdx.x;
    int t = threadIdx.x;
    __shared__ __align__(16) unsigned short qs[768];
    __shared__ float sc[16][48];
    __shared__ float lnz[KTOT][16];
    __shared__ float wb[16][17];
    __shared__ float pgs[16], pbs[16];
    __shared__ int sidx[KTOT];
    __shared__ float pacc[96][8];

    wb[t >> 4][t & 15] = Wbp[t];
    if (t < 96) ((short8*)qs)[t] = ((const short8*)(qkvg + (size_t)n * 3072))[t];
    if (t >= 96 && t < 96 + KTOT) sidx[t - 96] = idx[n * KTOT + (t - 96)];
    if (t >= 160 && t < 176) pgs[t - 160] = pg[t - 160];
    if (t >= 176 && t < 192) pbs[t - 176] = pb[t - 176];
    __syncthreads();

    if (t < KTOT) {
        const f32x4* z = (const f32x4*)(Z + ((size_t)n * NTOK + sidx[t]) * CP);
        f32x4 z0 = z[0], z1 = z[1], z2 = z[2], z3 = z[3];
        float v[16];
#pragma unroll
        for (int e = 0; e < 4; ++e) { v[e] = z0[e]; v[4 + e] = z1[e]; v[8 + e] = z2[e]; v[12 + e] = z3[e]; }
        float s = 0.0f;
#pragma unroll
        for (int c = 0; c < 16; ++c) s += v[c];
        float mean = s * (1.0f / 16.0f);
        float s2 = 0.0f;
#pragma unroll
        for (int c = 0; c < 16; ++c) { float d = v[c] - mean; s2 += d * d; }
        float rstd = rsqrtf(s2 * (1.0f / 16.0f) + 1e-5f);
#pragma unroll
        for (int c = 0; c < 16; ++c) lnz[t][c] = (v[c] - mean) * rstd * pgs[c] + pbs[c];
    }
    __syncthreads();

    for (int task = t; task < NH * KTOT; task += 256) {
        int h = task / KTOT, k = task - h * KTOT;
        const short8* kp = (const short8*)((const unsigned short*)qkvg +
                                           (size_t)sidx[k] * 3072 + 768 + h * DH);
        const short8* qp = (const short8*)(qs + h * DH);
        float s = 0.0f;
#pragma unroll
        for (int j = 0; j < 6; ++j) {
            short8 kv = kp[j];
            short8 qv = qp[j];
#pragma unroll
            for (int e = 0; e < 8; ++e)
                s += bf2f((unsigned short)qv[e]) * bf2f((unsigned short)kv[e]);
        }
        float bias = 0.0f;
#pragma unroll
        for (int c = 0; c < 16; ++c) bias += lnz[k][c] * wb[c][h];
        sc[h][k] = s * SCALE_ + bias;
    }
    __syncthreads();

    {
        int h = t >> 4, l = t & 15;
        float v0 = sc[h][l];
        float v1 = sc[h][l + 16];
        float v2 = (l < 8) ? sc[h][l + 32] : -INFINITY;
        float mx = fmaxf(fmaxf(v0, v1), v2);
#pragma unroll
        for (int m = 8; m > 0; m >>= 1) mx = fmaxf(mx, __shfl_xor(mx, m, 16));
        float e0 = __expf(v0 - mx), e1 = __expf(v1 - mx);
        float e2 = (l < 8) ? __expf(v2 - mx) : 0.0f;
        float sm = e0 + e1 + e2;
#pragma unroll
        for (int m = 8; m > 0; m >>= 1) sm += __shfl_xor(sm, m, 16);
        float inv = 1.0f / sm;
        sc[h][l] = e0 * inv;
        sc[h][l + 16] = e1 * inv;
        if (l < 8) sc[h][l + 32] = e2 * inv;
    }
    __syncthreads();

    float acc[8] = {0, 0, 0, 0, 0, 0, 0, 0};
    const int half = (t >= 96) ? 1 : 0;
    const int tt = t - half * 96;
    if (t < 192) {
        int h = tt / 6, c6 = tt - h * 6;
        int d0 = c6 * 8;
        const unsigned short* vbase = (const unsigned short*)qkvg + 1536 + h * DH + d0;
        for (int k = half * 20; k < half * 20 + 20; ++k) {
            short8 vv = *(const short8*)(vbase + (size_t)sidx[k] * 3072);
            float w = sc[h][k];
#pragma unroll
            for (int e = 0; e < 8; ++e) acc[e] += w * bf2f((unsigned short)vv[e]);
        }
    }
    if (half && t < 192) {
#pragma unroll
        for (int e = 0; e < 8; ++e) pacc[tt][e] = acc[e];
    }
    __syncthreads();
    if (t < 96) {
        int h = t / 6, c6 = t - h * 6;
        int d0 = c6 * 8;
        short8 gv = *(const short8*)((const unsigned short*)qkvg +
                                     (size_t)n * 3072 + 2304 + h * DH + d0);
        short8 ov;
#pragma unroll
        for (int e = 0; e < 8; ++e) {
            float g = sigmoidf_(bf2f((unsigned short)gv[e]));
            ov[e] = (short)f2bf(g * (acc[e] + pacc[t][e]));
        }
        *(short8*)((unsigned short*)o2 + (size_t)n * CT + h * DH + d0) = ov;
    }
}

// ---------------------------------------------------------------------------
// Host orchestration
// ---------------------------------------------------------------------------
extern "C" void kernel_launch(void* const* d_in, const int* in_sizes, int n_in,
                              void* d_out, int out_size, void* d_ws, size_t ws_size,
                              hipStream_t stream) {
    const float* A_I  = (const float*)d_in[0];
    const float* S_I  = (const float*)d_in[1];
    const float* Z_II = (const float*)d_in[2];
    const float* X_L  = (const float*)d_in[3];
    const float* aln1_sln_g = (const float*)d_in[5];
    const float* aln1_sw    = (const float*)d_in[6];
    const float* aln1_sb    = (const float*)d_in[7];
    const float* aln1_shw   = (const float*)d_in[8];
    const float* Wq  = (const float*)d_in[9];
    const float* bq  = (const float*)d_in[10];
    const float* Wk  = (const float*)d_in[11];
    const float* Wv  = (const float*)d_in[12];
    const float* pair_ln_g = (const float*)d_in[13];
    const float* pair_ln_b = (const float*)d_in[14];
    const float* Wbp = (const float*)d_in[15];
    const float* Wg  = (const float*)d_in[16];
    const float* Wo  = (const float*)d_in[17];
    const float* sg_w = (const float*)d_in[18];
    const float* sg_b = (const float*)d_in[19];
    const float* aln2_sln_g = (const float*)d_in[20];
    const float* aln2_sw    = (const float*)d_in[21];
    const float* aln2_sb    = (const float*)d_in[22];
    const float* aln2_shw   = (const float*)d_in[23];
    const float* t_w1 = (const float*)d_in[24];
    const float* t_w2 = (const float*)d_in[25];
    const float* t_w3 = (const float*)d_in[26];
    const float* tsg_w = (const float*)d_in[27];
    const float* tsg_b = (const float*)d_in[28];
    (void)in_sizes; (void)n_in; (void)out_size; (void)ws_size;

    float* A = (float*)d_out;

    char* ws = (char*)d_ws;
    size_t off = 0;
    auto alloc = [&](size_t bytes) {
        void* p = ws + off;
        off += (bytes + 255) & ~(size_t)255;
        return p;
    };
    int*   idx    = (int*)  alloc(NTOK * KTOT * 4);
    __hip_bfloat16* S_bf  = (__hip_bfloat16*)alloc((size_t)NTOK * CS * 2);
    __hip_bfloat16* snb   = (__hip_bfloat16*)alloc((size_t)8 * NTOK * CS * 2);
    __hip_bfloat16* an    = (__hip_bfloat16*)alloc((size_t)NTOK * CT * 2);
    __hip_bfloat16* qkvg  = (__hip_bfloat16*)alloc((size_t)NTOK * 3072 * 2);
    __hip_bfloat16* sgateb= (__hip_bfloat16*)alloc((size_t)NBLK * NTOK * 1536 * 2);
    __hip_bfloat16* SIG   = (__hip_bfloat16*)alloc((size_t)8 * NTOK * CT * 2);
    __hip_bfloat16* SH    = (__hip_bfloat16*)alloc((size_t)8 * NTOK * CT * 2);
    __hip_bfloat16* o2    = (__hip_bfloat16*)alloc((size_t)NTOK * CT * 2);
    __hip_bfloat16* hb    = (__hip_bfloat16*)alloc((size_t)NTOK * 2 * CT * 2);
    float* qkvgbias = (float*)alloc((size_t)NBLK * 3072 * 4);
    float* sgbias   = (float*)alloc((size_t)NBLK * 1536 * 4);
    __hip_bfloat16* Wbuf = (__hip_bfloat16*)alloc((size_t)NBLK * WS_BLK * 2);

    hipMemcpyAsync(A, A_I, (size_t)NTOK * CT * 4, hipMemcpyDeviceToDevice, stream);

    // ---- merged prep (first in launch order) + conv dispatch ----
    {
        ConvPrep pa;
        int p = 0, ts = 0;
        auto add = [&](const float* s, size_t dstOff, int Kk, int Nn, int sstride) {
            pa.e[p].src = s; pa.e[p].dst = Wbuf + dstOff; pa.e[p].K = Kk;
            pa.e[p].N = Nn; pa.e[p].tstart = ts; pa.e[p].srcStride = sstride;
            ts += (Kk / 128) * (Nn / 128); ++p;
        };
        add(aln1_sw,  OFF_A1SW,           384, 768,  CS * CT);
        add(aln1_shw, OFF_A1SHW,          384, 768,  CS * CT);
        add(Wq, OFF_QKVG + 0 * 589824,    768, 768,  CT * CT);
        add(Wk, OFF_QKVG + 1 * 589824,    768, 768,  CT * CT);
        add(Wv, OFF_QKVG + 2 * 589824,    768, 768,  CT * CT);
        add(Wg, OFF_QKVG + 3 * 589824,    768, 768,  CT * CT);
        add(Wo, OFF_WO,                   768, 768,  CT * CT);
        add(sg_w,  OFF_SGT,               384, 768,  CS * CT);
        add(tsg_w, OFF_SGT + 768 * 384,   384, 768,  CS * CT);
        add(aln2_sw,  OFF_A2SW,           384, 768,  CS * CT);
        add(aln2_shw, OFF_A2SHW,          384, 768,  CS * CT);
        add(t_w1, OFF_TW1,                768, 1536, CT * 2 * CT);
        add(t_w2, OFF_TW2,                768, 1536, CT * 2 * CT);
        add(t_w3, OFF_TW3,                1536, 768, 2 * CT * CT);
        pa.X_L = X_L; pa.idx = idx;
        pa.S = S_I; pa.g1 = aln1_sln_g; pa.g2 = aln2_sln_g;
        pa.S_bf = S_bf; pa.snb = snb;
        pa.bq = bq; pa.sg_b = sg_b; pa.tsg_b = tsg_b;
        pa.qb = qkvgbias; pa.sb2 = sgbias;
        convprep_kernel<<<NPREPB + ts * NBLK, 256, 0, stream>>>(pa);
    }

    // ---- merged hoisted S-GEMMs (AdaLN z=16 + sgate z=4), one dispatch ----
    {
        HoistArgs ha;
        ha.snb = snb; ha.S_bf = S_bf; ha.Wbuf = Wbuf;
        ha.a1sb = aln1_sb; ha.a2sb = aln2_sb; ha.sgbias = sgbias;
        ha.SIG = SIG; ha.SH = SH; ha.sgateb = sgateb;
        gemmh_kernel<<<1536 + 768, 256, 0, stream>>>(ha);
    }

    for (int i = 0; i < NBLK; ++i) {
        const __hip_bfloat16* Wb_i = Wbuf + (size_t)i * WS_BLK;
        __hip_bfloat16* sg_i = sgateb + (size_t)i * NTOK * 1536;

        // ---- LocalAttentionPairBias ----
        adaapply_kernel<<<NTOK, 256, 0, stream>>>(
            A, SIG + (size_t)(2 * i) * NTOK * CT, SH + (size_t)(2 * i) * NTOK * CT, an);
        gemmw_kernel<<<dim3(48, 8), 256, 0, stream>>>(
            an, Wb_i + OFF_QKVG, qkvgbias + (size_t)i * 3072, qkvg, 768, 3072, 3072);
        attn_kernel<<<NTOK, 256, 0, stream>>>(
            qkvg, Z_II, idx, pair_ln_g + (size_t)i * CP, pair_ln_b + (size_t)i * CP,
            Wbp + (size_t)i * CP * NH, o2);
        gemm_kernel<3><<<dim3(12, 16, 4), 256, 0, stream>>>(
            o2, Wb_i + OFF_WO, nullptr, sg_i, 1536, A, nullptr, 768, 192, 768, 768);

        // ---- ConditionedTransitionBlock ----
        adaapply_kernel<<<NTOK, 256, 0, stream>>>(
            A, SIG + (size_t)(2 * i + 1) * NTOK * CT, SH + (size_t)(2 * i + 1) * NTOK * CT, an);
        gemm_kernel<2><<<dim3(24, 16, 1), 256, 0, stream>>>(
            an, Wb_i + OFF_TW1, Wb_i + OFF_TW2, nullptr, 0, nullptr, hb, 768, 768, 1536, 1536);
        gemm_kernel<3><<<dim3(12, 16, 4), 256, 0, stream>>>(
            hb, Wb_i + OFF_TW3, nullptr, sg_i + 768, 1536, A, nullptr, 1536, 384, 768, 768);
    }
}

// Round 17
// 371.451 us; speedup vs baseline: 1.3709x; 1.0599x over previous
//
#include <hip/hip_runtime.h>
#include <hip/hip_bf16.h>
#include <math.h>
#include <stdint.h>

#define NTOK 1024
#define CT   768
#define CS   384
#define CP   16
#define NH   16
#define DH   48
#define NBLK 4
#define NL   8
#define NKEY 32
#define KTOT 40
#define SCALE_ 0.14433756729740643f   // 1/sqrt(48)

// Wbuf per-block element offsets (bf16 elements)
#define WS_BLK      8257536
#define OFF_A1SW    0
#define OFF_A1SHW   294912
#define OFF_QKVG    589824
#define OFF_WO      2949120
#define OFF_SGT     3538944
#define OFF_A2SW    4128768
#define OFF_A2SHW   4423680
#define OFF_TW1     4718592
#define OFF_TW2     5898240
#define OFF_TW3     7077888

#define NCONVT 504          // 128x128 conv tiles per weight-block
#define NPREPB 1328         // 256 topk + 1024 sprep + 48 biasprep

typedef __attribute__((ext_vector_type(8))) short short8;
typedef __attribute__((ext_vector_type(4))) float f32x4;

#define AS1 __attribute__((address_space(1)))
#define AS3 __attribute__((address_space(3)))

__device__ __forceinline__ float sigmoidf_(float x) {
    return 1.0f / (1.0f + __expf(-x));
}
__device__ __forceinline__ float bf2f(unsigned short u) {
    union { unsigned int i; float f; } v; v.i = (unsigned int)u << 16; return v.f;
}
__device__ __forceinline__ unsigned short f2bf(float f) {
    return __bfloat16_as_ushort(__float2bfloat16(f));
}

__device__ __forceinline__ void gl_lds16(const void* g, void* l) {
    __builtin_amdgcn_global_load_lds((const AS1 void*)(uintptr_t)g,
                                     (AS3 void*)(uintptr_t)l, 16, 0, 0);
}

// ---------------------------------------------------------------------------
// Merged conv+prep kernel. Blocks [0,1328): prep roles FIRST in launch order
// (long small blocks fill CUs, conv stream hides them). Blocks >= 1328:
// weight convert+transpose (in-register 8x8, no LDS).
// ---------------------------------------------------------------------------
struct ConvDesc { const float* src; __hip_bfloat16* dst; int K; int N; int tstart; int srcStride; };
struct ConvPrep {
    ConvDesc e[14];
    const float* X_L; int* idx;
    const float* S; const float* g1; const float* g2;
    __hip_bfloat16* S_bf; __hip_bfloat16* snb;
    const float* bq; const float* sg_b; const float* tsg_b;
    float* qb; float* sb2;
};

__global__ __launch_bounds__(256)
void convprep_kernel(ConvPrep pa) {
    __shared__ float ls[8];
    const int t = threadIdx.x;
    const int b = blockIdx.x;

    if (b >= NPREPB) {
        // ---- convT role ----
        int cb = b - NPREPB;
        int wblk = cb / NCONVT;
        int tt_all = cb % NCONVT;
        int ei = 0;
#pragma unroll
        for (int j = 1; j < 14; ++j) if (tt_all >= pa.e[j].tstart) ei = j;
        ConvDesc d = pa.e[ei];
        const float* src = d.src + (size_t)wblk * d.srcStride;
        unsigned short* dst = (unsigned short*)(d.dst + (size_t)wblk * WS_BLK);
        int tt = tt_all - d.tstart;
        int ntn = d.N / 128;
        int k0 = (tt / ntn) * 128, n0 = (tt % ntn) * 128;

        const int ck = t & 15;
        const int cn = t >> 4;
        const float* sp = src + (size_t)(k0 + ck * 8) * d.N + n0 + cn * 8;
        f32x4 va[8], vb[8];
#pragma unroll
        for (int r = 0; r < 8; ++r) {
            va[r] = *(const f32x4*)(sp + (size_t)r * d.N);
            vb[r] = *(const f32x4*)(sp + (size_t)r * d.N + 4);
        }
        unsigned short* dp = dst + (size_t)(n0 + cn * 8) * d.K + k0 + ck * 8;
#pragma unroll
        for (int j = 0; j < 8; ++j) {
            short8 o;
#pragma unroll
            for (int e = 0; e < 8; ++e) {
                float f = (j < 4) ? va[e][j] : vb[e][j - 4];
                o[e] = (short)f2bf(f);
            }
            *(short8*)(dp + (size_t)j * d.K) = o;
        }
        return;
    }

    if (b < 256) {
        // ---- topk: one wave per token ----
        const int w = t >> 6;
        const int l = t & 63;
        const int n = b * 4 + w;
        const float* X = pa.X_L;
        int* idx = pa.idx;

        const float x0 = X[n * 3 + 0], x1 = X[n * 3 + 1], x2 = X[n * 3 + 2];
        float d[16];
        unsigned long long lkey = ~0ull;
#pragma unroll
        for (int j = 0; j < 16; ++j) {
            int m = j * 64 + l;
            float dx = x0 - X[m * 3 + 0];
            float dy = x1 - X[m * 3 + 1];
            float dz = x2 - X[m * 3 + 2];
            float v = dx * dx + dy * dy + dz * dz;
            d[j] = v;
            unsigned long long key =
                ((unsigned long long)__float_as_uint(v) << 32) | (unsigned int)m;
            lkey = key < lkey ? key : lkey;
        }
        if (l < NL) {
            int loc = n + l - NL / 2;
            loc = loc < 0 ? 0 : (loc > NTOK - 1 ? NTOK - 1 : loc);
            idx[n * KTOT + l] = loc;
        }
        for (int it = 0; it < NKEY; ++it) {
            unsigned long long rk = lkey;
#pragma unroll
            for (int s = 32; s > 0; s >>= 1) {
                unsigned long long o = __shfl_xor(rk, s, 64);
                rk = o < rk ? o : rk;
            }
            unsigned int win = (unsigned int)rk;
            if (l == 0) idx[n * KTOT + NL + it] = (int)win;
            if ((int)(win & 63) == l) {
                int jw = (int)(win >> 6);
                unsigned long long nk = ~0ull;
#pragma unroll
                for (int j = 0; j < 16; ++j) {
                    if (j == jw) d[j] = INFINITY;
                    unsigned long long key =
                        ((unsigned long long)__float_as_uint(d[j]) << 32) |
                        (unsigned int)(j * 64 + l);
                    nk = key < nk ? key : nk;
                }
                lkey = nk;
            }
        }
        return;
    }

    if (b < 1280) {
        // ---- sprep (256 threads, 384 cols) ----
        int r = b - 256;
        int wid = t >> 6, l = t & 63;
        const float* S = pa.S;
        float v0 = S[r * CS + t];
        float v1 = (t < 128) ? S[r * CS + 256 + t] : 0.0f;
        float s = v0 + v1;
#pragma unroll
        for (int m = 32; m > 0; m >>= 1) s += __shfl_xor(s, m, 64);
        if (l == 0) ls[wid] = s;
        __syncthreads();
        float mean = (ls[0] + ls[1] + ls[2] + ls[3]) * (1.0f / CS);
        float d0 = v0 - mean, d1 = v1 - mean;
        float q = d0 * d0 + ((t < 128) ? d1 * d1 : 0.0f);
#pragma unroll
        for (int m = 32; m > 0; m >>= 1) q += __shfl_xor(q, m, 64);
        if (l == 0) ls[4 + wid] = q;
        __syncthreads();
        float rstd = rsqrtf((ls[4] + ls[5] + ls[6] + ls[7]) * (1.0f / CS) + 1e-5f);
        float ln0 = d0 * rstd, ln1 = d1 * rstd;
        pa.S_bf[r * CS + t] = __float2bfloat16(v0);
        if (t < 128) pa.S_bf[r * CS + 256 + t] = __float2bfloat16(v1);
#pragma unroll
        for (int j = 0; j < 8; ++j) {
            const float* g = ((j & 1) ? pa.g2 : pa.g1) + (j >> 1) * CS;
            size_t base = ((size_t)j * NTOK + r) * CS;
            pa.snb[base + t] = __float2bfloat16(ln0 * g[t]);
            if (t < 128) pa.snb[base + 256 + t] = __float2bfloat16(ln1 * g[256 + t]);
        }
        return;
    }

    // ---- biasprep ----
    {
        int tt = (b - 1280) * 256 + t;
        if (tt < NBLK * 3072) {
            int i = tt / 3072, c = tt % 3072;
            pa.qb[tt] = (c < 768) ? pa.bq[i * 768 + c] : 0.0f;
        }
        if (tt < NBLK * 1536) {
            int i = tt / 1536, c = tt % 1536;
            pa.sb2[tt] = (c < 768) ? pa.sg_b[i * 768 + c] : pa.tsg_b[i * 768 + c - 768];
        }
    }
}

// ---------------------------------------------------------------------------
// AdaLN apply: an = bf16( sigmoid(SIG) * LN(A) + SH ). One block per row.
// ---------------------------------------------------------------------------
__global__ __launch_bounds__(256)
void adaapply_kernel(const float* __restrict__ A,
                     const __hip_bfloat16* __restrict__ SIG,
                     const __hip_bfloat16* __restrict__ SH,
                     __hip_bfloat16* __restrict__ an) {
    int r = blockIdx.x, t = threadIdx.x;
    int wid = t >> 6, l = t & 63;
    __shared__ float ls[8];
    const float* ar = A + (size_t)r * CT;
    float v0 = ar[t], v1 = ar[t + 256], v2 = ar[t + 512];
    float s = v0 + v1 + v2;
#pragma unroll
    for (int m = 32; m > 0; m >>= 1) s += __shfl_xor(s, m, 64);
    if (l == 0) ls[wid] = s;
    __syncthreads();
    float mean = (ls[0] + ls[1] + ls[2] + ls[3]) * (1.0f / CT);
    float d0 = v0 - mean, d1 = v1 - mean, d2 = v2 - mean;
    float q = d0 * d0 + d1 * d1 + d2 * d2;
#pragma unroll
    for (int m = 32; m > 0; m >>= 1) q += __shfl_xor(q, m, 64);
    if (l == 0) ls[4 + wid] = q;
    __syncthreads();
    float rstd = rsqrtf((ls[4] + ls[5] + ls[6] + ls[7]) * (1.0f / CT) + 1e-5f);
    size_t base = (size_t)r * CT;
    float dd[3] = {d0, d1, d2};
#pragma unroll
    for (int k = 0; k < 3; ++k) {
        int c = t + k * 256;
        float sg = sigmoidf_(__bfloat162float(SIG[base + c]));
        float sh = __bfloat162float(SH[base + c]);
        an[base + c] = __float2bfloat16(sg * dd[k] * rstd + sh);
    }
}

// ---------------------------------------------------------------------------
// Merged hoisted S-GEMMs: AdaLN pre (16 groups, blocks<1536) + sgate pre
// (4 groups). Wide tile 128x64, BK=64, dbuf single-barrier, K=384.
// ---------------------------------------------------------------------------
struct HoistArgs {
    const __hip_bfloat16* snb; const __hip_bfloat16* S_bf;
    const __hip_bfloat16* Wbuf;
    const float* a1sb; const float* a2sb; const float* sgbias;
    __hip_bfloat16* SIG; __hip_bfloat16* SH; __hip_bfloat16* sgateb;
};

__device__ __forceinline__ void wide_body(
    const __hip_bfloat16* A, const __hip_bfloat16* B1, const float* cb,
    __hip_bfloat16* outp, int K, int ldo, int row0, int col0,
    char (*As)[16384], char (*Bs)[8192]) {
    const int tid = threadIdx.x;
    const int lane = tid & 63;
    const int wid = tid >> 6;
    const int srow = tid >> 3;
    const int sg_e = (((tid & 7) ^ (srow & 7)) << 3);
    const __hip_bfloat16* ag = A + (size_t)(row0 + srow) * K + sg_e;
    const __hip_bfloat16* bg = B1 + (size_t)(col0 + srow) * K + sg_e;
    const size_t r32K = (size_t)32 * K;
    f32x4 acc[2][4];
#pragma unroll
    for (int i = 0; i < 2; ++i)
#pragma unroll
        for (int jj = 0; jj < 4; ++jj) acc[i][jj] = (f32x4){0.f, 0.f, 0.f, 0.f};
    const int l15 = lane & 15;
    const int lhi = lane >> 4;
    const int nIter = K >> 6;
    auto STAGE = [&](int bi) {
        char* al = As[bi] + tid * 16;
        char* bl = Bs[bi] + tid * 16;
        gl_lds16(ag, al);
        gl_lds16(ag + r32K, al + 4096);
        gl_lds16(ag + 2 * r32K, al + 8192);
        gl_lds16(ag + 3 * r32K, al + 12288);
        gl_lds16(bg, bl);
        gl_lds16(bg + r32K, bl + 4096);
        ag += 64; bg += 64;
    };
    STAGE(0);
    for (int it = 0; it < nIter; ++it) {
        __syncthreads();
        if (it + 1 < nIter) STAGE((it + 1) & 1);
        const char* Ab = As[it & 1];
        const char* Bb = Bs[it & 1];
#pragma unroll
        for (int kk = 0; kk < 2; ++kk) {
            const int c = lhi + 4 * kk;
            short8 a[2], bv[4];
#pragma unroll
            for (int mi = 0; mi < 2; ++mi) {
                int ra = wid * 32 + mi * 16 + l15;
                a[mi] = *(const short8*)(Ab + ra * 128 + (((c ^ (ra & 7)) << 4)));
            }
#pragma unroll
            for (int ni = 0; ni < 4; ++ni) {
                int rb = ni * 16 + l15;
                bv[ni] = *(const short8*)(Bb + rb * 128 + (((c ^ (rb & 7)) << 4)));
            }
#pragma unroll
            for (int mi = 0; mi < 2; ++mi)
#pragma unroll
                for (int ni = 0; ni < 4; ++ni)
                    acc[mi][ni] = __builtin_amdgcn_mfma_f32_16x16x32_bf16(
                        a[mi], bv[ni], acc[mi][ni], 0, 0, 0);
        }
    }
#pragma unroll
    for (int mi = 0; mi < 2; ++mi)
#pragma unroll
        for (int ni = 0; ni < 4; ++ni) {
            int col = col0 + ni * 16 + l15;
            int rbase = row0 + wid * 32 + mi * 16 + lhi * 4;
            float cbv = cb ? cb[col] : 0.0f;
            f32x4 v = acc[mi][ni];
#pragma unroll
            for (int r = 0; r < 4; ++r)
                outp[(size_t)(rbase + r) * ldo + col] = __float2bfloat16(v[r] + cbv);
        }
}

__global__ __launch_bounds__(256)
void gemmh_kernel(HoistArgs ha) {
    __shared__ __align__(16) char As[2][16384];
    __shared__ __align__(16) char Bs[2][8192];
    int b = blockIdx.x;
    if (b < 1536) {
        int z = b / 96, rem = b % 96;
        int y = rem / 12, x = rem % 12;
        int j = z & 7, half = z >> 3;
        const __hip_bfloat16* A = ha.snb + (size_t)j * NTOK * CS;
        const __hip_bfloat16* B1 = ha.Wbuf + (size_t)(j >> 1) * WS_BLK
            + ((j & 1) ? OFF_A2SW : OFF_A1SW)
            + (size_t)half * (OFF_A1SHW - OFF_A1SW);
        const float* cb = half ? nullptr : (((j & 1) ? ha.a2sb : ha.a1sb) + (j >> 1) * CT);
        __hip_bfloat16* outp = (half ? ha.SH : ha.SIG) + (size_t)j * NTOK * CT;
        wide_body(A, B1, cb, outp, CS, 768, y * 128, x * 64, As, Bs);
    } else {
        int b2 = b - 1536;
        int z = b2 / 192, rem = b2 % 192;
        int y = rem / 24, x = rem % 24;
        const __hip_bfloat16* B1 = ha.Wbuf + OFF_SGT + (size_t)z * WS_BLK;
        wide_body(ha.S_bf, B1, ha.sgbias + z * 1536,
                  ha.sgateb + (size_t)z * NTOK * 1536, CS, 1536,
                  y * 128, x * 64, As, Bs);
    }
}

// ---------------------------------------------------------------------------
// Wide bf16 MFMA GEMM 128x64 (QKVG). Dbuf single-barrier.
// ---------------------------------------------------------------------------
__global__ __launch_bounds__(256)
void gemmw_kernel(const __hip_bfloat16* A, const __hip_bfloat16* B1,
                  const float* cb, __hip_bfloat16* outb,
                  int K, int N, int ldo) {
    __shared__ __align__(16) char As[2][16384];
    __shared__ __align__(16) char Bs[2][8192];
    wide_body(A, B1, cb, outb, K, ldo, blockIdx.y * 128, blockIdx.x * 64, As, Bs);
}

// ---------------------------------------------------------------------------
// 64x64 GEMM, dbuf single-barrier.
// MODE 2: outb = bf16( silu(acc1) * acc2 )    (dual B)
// MODE 3: atomicAdd(outf, sigmoid(auxb)*acc1) (gated residual, split-K z=2)
// ---------------------------------------------------------------------------
template <int MODE>
__global__ __launch_bounds__(256)
void gemm_kernel(const __hip_bfloat16* __restrict__ A,
                 const __hip_bfloat16* B1,
                 const __hip_bfloat16* B2,
                 const __hip_bfloat16* __restrict__ auxb, int ld_aux,
                 float* __restrict__ outf,
                 __hip_bfloat16* outb,
                 int Kfull, int Ksub, int N, int ldo) {
    constexpr bool DUAL = (MODE == 2);
    __shared__ __align__(16) char As[2][8192];
    __shared__ __align__(16) char Bs[2][8192];
    __shared__ __align__(16) char Bs2[DUAL ? 2 : 1][DUAL ? 8192 : 16];

    const int tid = threadIdx.x;
    const int lane = tid & 63;
    const int wid = tid >> 6;
    const int wr = wid >> 1, wc = wid & 1;
    const int row0 = blockIdx.y * 64;
    const int col0 = blockIdx.x * 64;
    const int koff = blockIdx.z * Ksub;

    const int srow = tid >> 3;
    const int sg_e = (((tid & 7) ^ (srow & 7)) << 3);
    const __hip_bfloat16* ag = A + (size_t)(row0 + srow) * Kfull + koff + sg_e;
    const __hip_bfloat16* bg = B1 + (size_t)(col0 + srow) * Kfull + koff + sg_e;
    const __hip_bfloat16* bg2 = DUAL ? (B2 + (size_t)(col0 + srow) * Kfull + koff + sg_e) : nullptr;
    const size_t r32K = (size_t)32 * Kfull;

    auto STAGE = [&](int bi) {
        gl_lds16(ag, As[bi] + tid * 16);
        gl_lds16(ag + r32K, As[bi] + 4096 + tid * 16);
        gl_lds16(bg, Bs[bi] + tid * 16);
        gl_lds16(bg + r32K, Bs[bi] + 4096 + tid * 16);
        if (DUAL) {
            gl_lds16(bg2, Bs2[bi] + tid * 16);
            gl_lds16(bg2 + r32K, Bs2[bi] + 4096 + tid * 16);
            bg2 += 64;
        }
        ag += 64; bg += 64;
    };

    f32x4 acc[2][2];
    f32x4 acc2[2][2];
#pragma unroll
    for (int i = 0; i < 2; ++i)
#pragma unroll
        for (int j = 0; j < 2; ++j) {
            acc[i][j] = (f32x4){0.f, 0.f, 0.f, 0.f};
            acc2[i][j] = (f32x4){0.f, 0.f, 0.f, 0.f};
        }

    const int l15 = lane & 15;
    const int lhi = lane >> 4;
    const int nIter = Ksub >> 6;

    STAGE(0);
    for (int it = 0; it < nIter; ++it) {
        __syncthreads();
        if (it + 1 < nIter) STAGE((it + 1) & 1);
        const char* Ab = As[it & 1];
        const char* Bb = Bs[it & 1];
        const char* Cb = DUAL ? Bs2[it & 1] : nullptr;
#pragma unroll
        for (int kk = 0; kk < 2; ++kk) {
            const int c = lhi + 4 * kk;
            const int ra0 = wr * 32 + l15, ra1 = ra0 + 16;
            const int rb0 = wc * 32 + l15, rb1 = rb0 + 16;
            short8 a0 = *(const short8*)(Ab + ra0 * 128 + (((c ^ (ra0 & 7)) << 4)));
            short8 a1 = *(const short8*)(Ab + ra1 * 128 + (((c ^ (ra1 & 7)) << 4)));
            short8 b0 = *(const short8*)(Bb + rb0 * 128 + (((c ^ (rb0 & 7)) << 4)));
            short8 b1 = *(const short8*)(Bb + rb1 * 128 + (((c ^ (rb1 & 7)) << 4)));
            acc[0][0] = __builtin_amdgcn_mfma_f32_16x16x32_bf16(a0, b0, acc[0][0], 0, 0, 0);
            acc[0][1] = __builtin_amdgcn_mfma_f32_16x16x32_bf16(a0, b1, acc[0][1], 0, 0, 0);
            acc[1][0] = __builtin_amdgcn_mfma_f32_16x16x32_bf16(a1, b0, acc[1][0], 0, 0, 0);
            acc[1][1] = __builtin_amdgcn_mfma_f32_16x16x32_bf16(a1, b1, acc[1][1], 0, 0, 0);
            if (DUAL) {
                short8 c0 = *(const short8*)(Cb + rb0 * 128 + (((c ^ (rb0 & 7)) << 4)));
                short8 c1 = *(const short8*)(Cb + rb1 * 128 + (((c ^ (rb1 & 7)) << 4)));
                acc2[0][0] = __builtin_amdgcn_mfma_f32_16x16x32_bf16(a0, c0, acc2[0][0], 0, 0, 0);
                acc2[0][1] = __builtin_amdgcn_mfma_f32_16x16x32_bf16(a0, c1, acc2[0][1], 0, 0, 0);
                acc2[1][0] = __builtin_amdgcn_mfma_f32_16x16x32_bf16(a1, c0, acc2[1][0], 0, 0, 0);
                acc2[1][1] = __builtin_amdgcn_mfma_f32_16x16x32_bf16(a1, c1, acc2[1][1], 0, 0, 0);
            }
        }
    }

#pragma unroll
    for (int mi = 0; mi < 2; ++mi)
#pragma unroll
        for (int ni = 0; ni < 2; ++ni) {
            f32x4 v1 = acc[mi][ni];
            f32x4 v2 = acc2[mi][ni];
            int col = col0 + wc * 32 + ni * 16 + l15;
            int rbase = row0 + wr * 32 + mi * 16 + lhi * 4;
#pragma unroll
            for (int r = 0; r < 4; ++r) {
                int row = rbase + r;
                size_t o = (size_t)row * ldo + col;
                if (MODE == 2) {
                    float x = v1[r];
                    outb[o] = __float2bfloat16(x * sigmoidf_(x) * v2[r]);
                } else {
                    float g = sigmoidf_(__bfloat162float(auxb[(size_t)row * ld_aux + col]));
                    atomicAdd(&outf[o], g * v1[r]);
                }
            }
        }
}

// ---------------------------------------------------------------------------
// Attention + fused pair bias. One block per token. bf16 qkvg [1024][3072].
// ---------------------------------------------------------------------------
__global__ __launch_bounds__(256)
void attn_kernel(const __hip_bfloat16* __restrict__ qkvg,
                 const float* __restrict__ Z,
                 const int* __restrict__ idx,
                 const float* __restrict__ pg, const float* __restrict__ pb,
                 const float* __restrict__ Wbp,
                 __hip_bfloat16* __restrict__ o2) {
    int n = blockIdx.x;
    int t = threadIdx.x;
    __shared__ __align__(16) unsigned short qs[768];
    __shared__ float sc[16][48];
    __shared__ float lnz[KTOT][16];
    __shared__ float wb[16][17];
    __shared__ float pgs[16], pbs[16];
    __shared__ int sidx[KTOT];
    __shared__ float pacc[96][8];

    wb[t >> 4][t & 15] = Wbp[t];
    if (t < 96) ((short8*)qs)[t] = ((const short8*)(qkvg + (size_t)n * 3072))[t];
    if (t >= 96 && t < 96 + KTOT) sidx[t - 96] = idx[n * KTOT + (t - 96)];
    if (t >= 160 && t < 176) pgs[t - 160] = pg[t - 160];
    if (t >= 176 && t < 192) pbs[t - 176] = pb[t - 176];
    __syncthreads();

    if (t < KTOT) {
        const f32x4* z = (const f32x4*)(Z + ((size_t)n * NTOK + sidx[t]) * CP);
        f32x4 z0 = z[0], z1 = z[1], z2 = z[2], z3 = z[3];
        float v[16];
#pragma unroll
        for (int e = 0; e < 4; ++e) { v[e] = z0[e]; v[4 + e] = z1[e]; v[8 + e] = z2[e]; v[12 + e] = z3[e]; }
        float s = 0.0f;
#pragma unroll
        for (int c = 0; c < 16; ++c) s += v[c];
        float mean = s * (1.0f / 16.0f);
        float s2 = 0.0f;
#pragma unroll
        for (int c = 0; c < 16; ++c) { float d = v[c] - mean; s2 += d * d; }
        float rstd = rsqrtf(s2 * (1.0f / 16.0f) + 1e-5f);
#pragma unroll
        for (int c = 0; c < 16; ++c) lnz[t][c] = (v[c] - mean) * rstd * pgs[c] + pbs[c];
    }
    __syncthreads();

    for (int task = t; task < NH * KTOT; task += 256) {
        int h = task / KTOT, k = task - h * KTOT;
        const short8* kp = (const short8*)((const unsigned short*)qkvg +
                                           (size_t)sidx[k] * 3072 + 768 + h * DH);
        const short8* qp = (const short8*)(qs + h * DH);
        float s = 0.0f;
#pragma unroll
        for (int j = 0; j < 6; ++j) {
            short8 kv = kp[j];
            short8 qv = qp[j];
#pragma unroll
            for (int e = 0; e < 8; ++e)
                s += bf2f((unsigned short)qv[e]) * bf2f((unsigned short)kv[e]);
        }
        float bias = 0.0f;
#pragma unroll
        for (int c = 0; c < 16; ++c) bias += lnz[k][c] * wb[c][h];
        sc[h][k] = s * SCALE_ + bias;
    }
    __syncthreads();

    {
        int h = t >> 4, l = t & 15;
        float v0 = sc[h][l];
        float v1 = sc[h][l + 16];
        float v2 = (l < 8) ? sc[h][l + 32] : -INFINITY;
        float mx = fmaxf(fmaxf(v0, v1), v2);
#pragma unroll
        for (int m = 8; m > 0; m >>= 1) mx = fmaxf(mx, __shfl_xor(mx, m, 16));
        float e0 = __expf(v0 - mx), e1 = __expf(v1 - mx);
        float e2 = (l < 8) ? __expf(v2 - mx) : 0.0f;
        float sm = e0 + e1 + e2;
#pragma unroll
        for (int m = 8; m > 0; m >>= 1) sm += __shfl_xor(sm, m, 16);
        float inv = 1.0f / sm;
        sc[h][l] = e0 * inv;
        sc[h][l + 16] = e1 * inv;
        if (l < 8) sc[h][l + 32] = e2 * inv;
    }
    __syncthreads();

    float acc[8] = {0, 0, 0, 0, 0, 0, 0, 0};
    const int half = (t >= 96) ? 1 : 0;
    const int tt = t - half * 96;
    if (t < 192) {
        int h = tt / 6, c6 = tt - h * 6;
        int d0 = c6 * 8;
        const unsigned short* vbase = (const unsigned short*)qkvg + 1536 + h * DH + d0;
        for (int k = half * 20; k < half * 20 + 20; ++k) {
            short8 vv = *(const short8*)(vbase + (size_t)sidx[k] * 3072);
            float w = sc[h][k];
#pragma unroll
            for (int e = 0; e < 8; ++e) acc[e] += w * bf2f((unsigned short)vv[e]);
        }
    }
    if (half && t < 192) {
#pragma unroll
        for (int e = 0; e < 8; ++e) pacc[tt][e] = acc[e];
    }
    __syncthreads();
    if (t < 96) {
        int h = t / 6, c6 = t - h * 6;
        int d0 = c6 * 8;
        short8 gv = *(const short8*)((const unsigned short*)qkvg +
                                     (size_t)n * 3072 + 2304 + h * DH + d0);
        short8 ov;
#pragma unroll
        for (int e = 0; e < 8; ++e) {
            float g = sigmoidf_(bf2f((unsigned short)gv[e]));
            ov[e] = (short)f2bf(g * (acc[e] + pacc[t][e]));
        }
        *(short8*)((unsigned short*)o2 + (size_t)n * CT + h * DH + d0) = ov;
    }
}

// ---------------------------------------------------------------------------
// Host orchestration
// ---------------------------------------------------------------------------
extern "C" void kernel_launch(void* const* d_in, const int* in_sizes, int n_in,
                              void* d_out, int out_size, void* d_ws, size_t ws_size,
                              hipStream_t stream) {
    const float* A_I  = (const float*)d_in[0];
    const float* S_I  = (const float*)d_in[1];
    const float* Z_II = (const float*)d_in[2];
    const float* X_L  = (const float*)d_in[3];
    const float* aln1_sln_g = (const float*)d_in[5];
    const float* aln1_sw    = (const float*)d_in[6];
    const float* aln1_sb    = (const float*)d_in[7];
    const float* aln1_shw   = (const float*)d_in[8];
    const float* Wq  = (const float*)d_in[9];
    const float* bq  = (const float*)d_in[10];
    const float* Wk  = (const float*)d_in[11];
    const float* Wv  = (const float*)d_in[12];
    const float* pair_ln_g = (const float*)d_in[13];
    const float* pair_ln_b = (const float*)d_in[14];
    const float* Wbp = (const float*)d_in[15];
    const float* Wg  = (const float*)d_in[16];
    const float* Wo  = (const float*)d_in[17];
    const float* sg_w = (const float*)d_in[18];
    const float* sg_b = (const float*)d_in[19];
    const float* aln2_sln_g = (const float*)d_in[20];
    const float* aln2_sw    = (const float*)d_in[21];
    const float* aln2_sb    = (const float*)d_in[22];
    const float* aln2_shw   = (const float*)d_in[23];
    const float* t_w1 = (const float*)d_in[24];
    const float* t_w2 = (const float*)d_in[25];
    const float* t_w3 = (const float*)d_in[26];
    const float* tsg_w = (const float*)d_in[27];
    const float* tsg_b = (const float*)d_in[28];
    (void)in_sizes; (void)n_in; (void)out_size; (void)ws_size;

    float* A = (float*)d_out;

    char* ws = (char*)d_ws;
    size_t off = 0;
    auto alloc = [&](size_t bytes) {
        void* p = ws + off;
        off += (bytes + 255) & ~(size_t)255;
        return p;
    };
    int*   idx    = (int*)  alloc(NTOK * KTOT * 4);
    __hip_bfloat16* S_bf  = (__hip_bfloat16*)alloc((size_t)NTOK * CS * 2);
    __hip_bfloat16* snb   = (__hip_bfloat16*)alloc((size_t)8 * NTOK * CS * 2);
    __hip_bfloat16* an    = (__hip_bfloat16*)alloc((size_t)NTOK * CT * 2);
    __hip_bfloat16* qkvg  = (__hip_bfloat16*)alloc((size_t)NTOK * 3072 * 2);
    __hip_bfloat16* sgateb= (__hip_bfloat16*)alloc((size_t)NBLK * NTOK * 1536 * 2);
    __hip_bfloat16* SIG   = (__hip_bfloat16*)alloc((size_t)8 * NTOK * CT * 2);
    __hip_bfloat16* SH    = (__hip_bfloat16*)alloc((size_t)8 * NTOK * CT * 2);
    __hip_bfloat16* o2    = (__hip_bfloat16*)alloc((size_t)NTOK * CT * 2);
    __hip_bfloat16* hb    = (__hip_bfloat16*)alloc((size_t)NTOK * 2 * CT * 2);
    float* qkvgbias = (float*)alloc((size_t)NBLK * 3072 * 4);
    float* sgbias   = (float*)alloc((size_t)NBLK * 1536 * 4);
    __hip_bfloat16* Wbuf = (__hip_bfloat16*)alloc((size_t)NBLK * WS_BLK * 2);

    hipMemcpyAsync(A, A_I, (size_t)NTOK * CT * 4, hipMemcpyDeviceToDevice, stream);

    // ---- merged prep (first in launch order) + conv dispatch ----
    {
        ConvPrep pa;
        int p = 0, ts = 0;
        auto add = [&](const float* s, size_t dstOff, int Kk, int Nn, int sstride) {
            pa.e[p].src = s; pa.e[p].dst = Wbuf + dstOff; pa.e[p].K = Kk;
            pa.e[p].N = Nn; pa.e[p].tstart = ts; pa.e[p].srcStride = sstride;
            ts += (Kk / 128) * (Nn / 128); ++p;
        };
        add(aln1_sw,  OFF_A1SW,           384, 768,  CS * CT);
        add(aln1_shw, OFF_A1SHW,          384, 768,  CS * CT);
        add(Wq, OFF_QKVG + 0 * 589824,    768, 768,  CT * CT);
        add(Wk, OFF_QKVG + 1 * 589824,    768, 768,  CT * CT);
        add(Wv, OFF_QKVG + 2 * 589824,    768, 768,  CT * CT);
        add(Wg, OFF_QKVG + 3 * 589824,    768, 768,  CT * CT);
        add(Wo, OFF_WO,                   768, 768,  CT * CT);
        add(sg_w,  OFF_SGT,               384, 768,  CS * CT);
        add(tsg_w, OFF_SGT + 768 * 384,   384, 768,  CS * CT);
        add(aln2_sw,  OFF_A2SW,           384, 768,  CS * CT);
        add(aln2_shw, OFF_A2SHW,          384, 768,  CS * CT);
        add(t_w1, OFF_TW1,                768, 1536, CT * 2 * CT);
        add(t_w2, OFF_TW2,                768, 1536, CT * 2 * CT);
        add(t_w3, OFF_TW3,                1536, 768, 2 * CT * CT);
        pa.X_L = X_L; pa.idx = idx;
        pa.S = S_I; pa.g1 = aln1_sln_g; pa.g2 = aln2_sln_g;
        pa.S_bf = S_bf; pa.snb = snb;
        pa.bq = bq; pa.sg_b = sg_b; pa.tsg_b = tsg_b;
        pa.qb = qkvgbias; pa.sb2 = sgbias;
        convprep_kernel<<<NPREPB + ts * NBLK, 256, 0, stream>>>(pa);
    }

    // ---- merged hoisted S-GEMMs (AdaLN z=16 + sgate z=4), one dispatch ----
    {
        HoistArgs ha;
        ha.snb = snb; ha.S_bf = S_bf; ha.Wbuf = Wbuf;
        ha.a1sb = aln1_sb; ha.a2sb = aln2_sb; ha.sgbias = sgbias;
        ha.SIG = SIG; ha.SH = SH; ha.sgateb = sgateb;
        gemmh_kernel<<<1536 + 768, 256, 0, stream>>>(ha);
    }

    for (int i = 0; i < NBLK; ++i) {
        const __hip_bfloat16* Wb_i = Wbuf + (size_t)i * WS_BLK;
        __hip_bfloat16* sg_i = sgateb + (size_t)i * NTOK * 1536;

        // ---- LocalAttentionPairBias ----
        adaapply_kernel<<<NTOK, 256, 0, stream>>>(
            A, SIG + (size_t)(2 * i) * NTOK * CT, SH + (size_t)(2 * i) * NTOK * CT, an);
        gemmw_kernel<<<dim3(48, 8), 256, 0, stream>>>(
            an, Wb_i + OFF_QKVG, qkvgbias + (size_t)i * 3072, qkvg, 768, 3072, 3072);
        attn_kernel<<<NTOK, 256, 0, stream>>>(
            qkvg, Z_II, idx, pair_ln_g + (size_t)i * CP, pair_ln_b + (size_t)i * CP,
            Wbp + (size_t)i * CP * NH, o2);
        gemm_kernel<3><<<dim3(12, 16, 2), 256, 0, stream>>>(
            o2, Wb_i + OFF_WO, nullptr, sg_i, 1536, A, nullptr, 768, 384, 768, 768);

        // ---- ConditionedTransitionBlock ----
        adaapply_kernel<<<NTOK, 256, 0, stream>>>(
            A, SIG + (size_t)(2 * i + 1) * NTOK * CT, SH + (size_t)(2 * i + 1) * NTOK * CT, an);
        gemm_kernel<2><<<dim3(24, 16, 1), 256, 0, stream>>>(
            an, Wb_i + OFF_TW1, Wb_i + OFF_TW2, nullptr, 0, nullptr, hb, 768, 768, 1536, 1536);
        gemm_kernel<3><<<dim3(12, 16, 2), 256, 0, stream>>>(
            hb, Wb_i + OFF_TW3, nullptr, sg_i + 768, 1536, A, nullptr, 1536, 384, 768, 768);
    }
}